// Round 1
// baseline (964.925 us; speedup 1.0000x reference)
//
#include <hip/hip_runtime.h>
#include <math.h>

#define BG   128            // graphs
#define NPER 1024           // nodes per graph, level 0
#define HDIM 128            // hidden
#define NEDGE (BG * NPER * 8)
#define NMAX (BG * NPER)    // 131072

// ---------------------------------------------------------------------------
// small utility kernels
// ---------------------------------------------------------------------------

__global__ __launch_bounds__(128) void pnorm_kernel(
    const float* __restrict__ p1, const float* __restrict__ p2,
    const float* __restrict__ p3, float* __restrict__ pn) {
  const float* p = blockIdx.x == 0 ? p1 : (blockIdx.x == 1 ? p2 : p3);
  __shared__ float red[128];
  int t = threadIdx.x;
  float v = p[t];
  red[t] = v * v;
  __syncthreads();
  for (int off = 64; off; off >>= 1) {
    if (t < off) red[t] += red[t + off];
    __syncthreads();
  }
  if (t == 0) pn[blockIdx.x] = sqrtf(red[0]);
}

__global__ __launch_bounds__(256) void copy_edges_kernel(
    const int* __restrict__ er, const int* __restrict__ ec,
    int* __restrict__ cr, int* __restrict__ cc) {
  int e = blockIdx.x * 256 + threadIdx.x;
  cr[e] = er[e];
  cc[e] = ec[e];
}

__global__ __launch_bounds__(256) void count_kernel(
    const int* __restrict__ cc, int* __restrict__ cnt) {
  int e = blockIdx.x * 256 + threadIdx.x;
  int c = cc[e];
  if (c >= 0) atomicAdd(&cnt[c], 1);
}

__global__ __launch_bounds__(256) void dinv_kernel(
    const int* __restrict__ cnt, float* __restrict__ dinv) {
  int i = blockIdx.x * 256 + threadIdx.x;
  dinv[i] = rsqrtf((float)cnt[i] + 1.0f);
}

// ---------------------------------------------------------------------------
// exclusive scan (3 kernels): 1024 elements per block
// ---------------------------------------------------------------------------

__global__ __launch_bounds__(256) void scan1_kernel(
    const int* __restrict__ cnt, int* __restrict__ part) {
  __shared__ int red[256];
  int t = threadIdx.x;
  const int4* c4 = (const int4*)(cnt + (size_t)blockIdx.x * 1024);
  int4 v = c4[t];
  red[t] = v.x + v.y + v.z + v.w;
  __syncthreads();
  for (int off = 128; off; off >>= 1) {
    if (t < off) red[t] += red[t + off];
    __syncthreads();
  }
  if (t == 0) part[blockIdx.x] = red[0];
}

__global__ __launch_bounds__(256) void scan2_kernel(int* part, int nb) {
  __shared__ int s[256];
  int t = threadIdx.x;
  int v = (t < nb) ? part[t] : 0;
  s[t] = v;
  __syncthreads();
  for (int off = 1; off < 256; off <<= 1) {
    int u = (t >= off) ? s[t - off] : 0;
    __syncthreads();
    s[t] += u;
    __syncthreads();
  }
  if (t < nb) part[t] = s[t] - v;       // exclusive
  if (t == nb - 1) part[nb] = s[t];     // grand total
}

__global__ __launch_bounds__(256) void scan3_kernel(
    const int* __restrict__ cnt, const int* __restrict__ part,
    int* __restrict__ col_ptr, int* __restrict__ cursor, int n) {
  __shared__ int s[256];
  int t = threadIdx.x;
  int b = blockIdx.x;
  const int4* c4 = (const int4*)(cnt + (size_t)b * 1024);
  int4 v = c4[t];
  int local = v.x + v.y + v.z + v.w;
  s[t] = local;
  __syncthreads();
  for (int off = 1; off < 256; off <<= 1) {
    int u = (t >= off) ? s[t - off] : 0;
    __syncthreads();
    s[t] += u;
    __syncthreads();
  }
  int excl = s[t] - local + part[b];
  int4 w;
  w.x = excl;
  w.y = w.x + v.x;
  w.z = w.y + v.y;
  w.w = w.z + v.z;
  int i4 = b * 256 + t;
  ((int4*)col_ptr)[i4] = w;
  ((int4*)cursor)[i4] = w;
  if (b == 0 && t == 0) col_ptr[n] = part[gridDim.x];
}

__global__ __launch_bounds__(256) void fill_kernel(
    const int* __restrict__ cc, int* __restrict__ cursor,
    int* __restrict__ eidx) {
  int e = blockIdx.x * 256 + threadIdx.x;
  int c = cc[e];
  if (c >= 0) {
    int pos = atomicAdd(&cursor[c], 1);
    eidx[pos] = e;
  }
}

// ---------------------------------------------------------------------------
// aggregation: z[c] = sum_{e: col=c} x[row_e]*dinv[row]*dinv[c] + x[c]*dinv[c]^2
// one 128-thread block per destination node; thread t = channel t
// ---------------------------------------------------------------------------

__global__ __launch_bounds__(128) void agg_kernel(
    const float* __restrict__ x, float* __restrict__ z,
    const int* __restrict__ cr, const int* __restrict__ eidx,
    const int* __restrict__ col_ptr, const float* __restrict__ dinv) {
  int c = blockIdx.x;
  int t = threadIdx.x;
  float dc = dinv[c];
  float acc = x[(size_t)c * HDIM + t] * dc * dc;
  int p0 = col_ptr[c], p1 = col_ptr[c + 1];
  for (int e = p0; e < p1; ++e) {
    int id = eidx[e];
    int r = cr[id];
    float coef = dinv[r] * dc;
    acc = fmaf(x[(size_t)r * HDIM + t], coef, acc);
  }
  z[(size_t)c * HDIM + t] = acc;
}

// ---------------------------------------------------------------------------
// conv: h = relu(z @ W + b), in-place on zh; also score[row] = h . p
// tile: 64 rows x 128 cols, block 256 (col_t=tid&31 -> 4 cols, row_t=tid>>5 -> 8 rows)
// z tile in LDS (32 KB -> up to 4 blocks/CU); W streamed via L1/L2
// ---------------------------------------------------------------------------

__global__ __launch_bounds__(256) void conv_kernel(
    float* __restrict__ zh, const float* __restrict__ W,
    const float* __restrict__ bias, const float* __restrict__ p,
    float* __restrict__ score) {
  __shared__ float sZ[64 * HDIM];
  int tid = threadIdx.x;
  size_t base = (size_t)blockIdx.x * 64 * HDIM;
  float4* sZ4 = (float4*)sZ;
  const float4* g4 = (const float4*)(zh + base);
  #pragma unroll
  for (int i = 0; i < 8; ++i) sZ4[i * 256 + tid] = g4[i * 256 + tid];
  __syncthreads();

  int col_t = tid & 31;
  int row_t = tid >> 5;
  int r0 = row_t * 8;
  const float4* W4 = (const float4*)W;

  float acc[8][4];
  #pragma unroll
  for (int r = 0; r < 8; ++r)
    #pragma unroll
    for (int c = 0; c < 4; ++c) acc[r][c] = 0.f;

  for (int k4 = 0; k4 < 32; ++k4) {
    float4 w0 = W4[(k4 * 4 + 0) * 32 + col_t];
    float4 w1 = W4[(k4 * 4 + 1) * 32 + col_t];
    float4 w2 = W4[(k4 * 4 + 2) * 32 + col_t];
    float4 w3 = W4[(k4 * 4 + 3) * 32 + col_t];
    #pragma unroll
    for (int r = 0; r < 8; ++r) {
      float4 zr = sZ4[(r0 + r) * 32 + k4];
      acc[r][0] = fmaf(zr.x, w0.x, acc[r][0]);
      acc[r][1] = fmaf(zr.x, w0.y, acc[r][1]);
      acc[r][2] = fmaf(zr.x, w0.z, acc[r][2]);
      acc[r][3] = fmaf(zr.x, w0.w, acc[r][3]);
      acc[r][0] = fmaf(zr.y, w1.x, acc[r][0]);
      acc[r][1] = fmaf(zr.y, w1.y, acc[r][1]);
      acc[r][2] = fmaf(zr.y, w1.z, acc[r][2]);
      acc[r][3] = fmaf(zr.y, w1.w, acc[r][3]);
      acc[r][0] = fmaf(zr.z, w2.x, acc[r][0]);
      acc[r][1] = fmaf(zr.z, w2.y, acc[r][1]);
      acc[r][2] = fmaf(zr.z, w2.z, acc[r][2]);
      acc[r][3] = fmaf(zr.z, w2.w, acc[r][3]);
      acc[r][0] = fmaf(zr.w, w3.x, acc[r][0]);
      acc[r][1] = fmaf(zr.w, w3.y, acc[r][1]);
      acc[r][2] = fmaf(zr.w, w3.z, acc[r][2]);
      acc[r][3] = fmaf(zr.w, w3.w, acc[r][3]);
    }
  }

  float4 bv = ((const float4*)bias)[col_t];
  float4 pv = ((const float4*)p)[col_t];
  float4* out4 = (float4*)(zh + base);
  #pragma unroll
  for (int r = 0; r < 8; ++r) {
    float hx = fmaxf(acc[r][0] + bv.x, 0.f);
    float hy = fmaxf(acc[r][1] + bv.y, 0.f);
    float hz = fmaxf(acc[r][2] + bv.z, 0.f);
    float hw = fmaxf(acc[r][3] + bv.w, 0.f);
    float part = hx * pv.x + hy * pv.y + hz * pv.z + hw * pv.w;
    #pragma unroll
    for (int sft = 1; sft < 32; sft <<= 1) part += __shfl_xor(part, sft);
    out4[(r0 + r) * 32 + col_t] = make_float4(hx, hy, hz, hw);
    if (col_t == 0) score[blockIdx.x * 64 + r0 + r] = part;
  }
}

// ---------------------------------------------------------------------------
// per-graph top-K (K = P/2) by bitonic sort, descending, tie-break lower index
// ---------------------------------------------------------------------------

__global__ __launch_bounds__(256) void topk_kernel(
    const float* __restrict__ score, const float* __restrict__ pnorm,
    int* __restrict__ sel, float* __restrict__ tanhv, int* __restrict__ newid,
    int P, int K) {
  __shared__ float sv[1024];
  __shared__ int si[1024];
  int g = blockIdx.x;
  int t = threadIdx.x;
  for (int i = t; i < P; i += 256) {
    sv[i] = score[(size_t)g * P + i];
    si[i] = i;
  }
  for (int size = 2; size <= P; size <<= 1) {
    for (int stride = size >> 1; stride; stride >>= 1) {
      __syncthreads();
      for (int i = t; i < P; i += 256) {
        int j = i ^ stride;
        if (j > i) {
          float a = sv[i], b = sv[j];
          int ia = si[i], ib = si[j];
          bool tFirst = (a > b) || (a == b && ia < ib);
          bool up = ((i & size) == 0);
          if (up ? !tFirst : tFirst) {
            sv[i] = b; sv[j] = a;
            si[i] = ib; si[j] = ia;
          }
        }
      }
    }
  }
  __syncthreads();
  float pn = pnorm[0];
  for (int j = t; j < K; j += 256) {
    float v = sv[j];
    int oldg = g * P + si[j];
    int newg = g * K + j;
    sel[newg] = oldg;
    tanhv[newg] = tanhf(v / pn);
    newid[oldg] = newg;
  }
}

__global__ __launch_bounds__(128) void gather_kernel(
    const float* __restrict__ h, const int* __restrict__ sel,
    const float* __restrict__ tanhv, float* __restrict__ xo) {
  int j = blockIdx.x;
  int t = threadIdx.x;
  int s = sel[j];
  float tv = tanhv[j];
  xo[(size_t)j * HDIM + t] = h[(size_t)s * HDIM + t] * tv;
}

__global__ __launch_bounds__(128) void readout_kernel(
    const float* __restrict__ xo, float* __restrict__ out, int K) {
  int g = blockIdx.x;
  int t = threadIdx.x;
  const float* xg = xo + (size_t)g * K * HDIM;
  float mx = -INFINITY, sm = 0.f;
  for (int j = 0; j < K; ++j) {
    float v = xg[(size_t)j * HDIM + t];
    mx = fmaxf(mx, v);
    sm += v;
  }
  out[g * 256 + t] += mx;
  out[g * 256 + 128 + t] += sm / (float)K;
}

__global__ __launch_bounds__(256) void relabel_kernel(
    int* __restrict__ cr, int* __restrict__ cc,
    const int* __restrict__ newid) {
  int e = blockIdx.x * 256 + threadIdx.x;
  int r = cr[e];
  if (r < 0) return;
  int nr = newid[r];
  int nc = newid[cc[e]];
  if (nr < 0 || nc < 0) {
    cr[e] = -1;
    cc[e] = -1;
  } else {
    cr[e] = nr;
    cc[e] = nc;
  }
}

// ---------------------------------------------------------------------------
// launch
// ---------------------------------------------------------------------------

extern "C" void kernel_launch(void* const* d_in, const int* in_sizes, int n_in,
                              void* d_out, int out_size, void* d_ws, size_t ws_size,
                              hipStream_t stream) {
  const float* x0 = (const float*)d_in[0];
  const int* erow = (const int*)d_in[1];
  const int* ecol = (const int*)d_in[2];
  const float* Wm[3] = {(const float*)d_in[3], (const float*)d_in[6], (const float*)d_in[9]};
  const float* bm[3] = {(const float*)d_in[4], (const float*)d_in[7], (const float*)d_in[10]};
  const float* pm[3] = {(const float*)d_in[5], (const float*)d_in[8], (const float*)d_in[11]};

  char* w = (char*)d_ws;
  size_t off = 0;
  auto alloc = [&](size_t bytes) -> void* {
    void* ptr = w + off;
    off = (off + bytes + 255) & ~(size_t)255;
    return ptr;
  };
  int* cur_row = (int*)alloc((size_t)NEDGE * 4);
  int* cur_col = (int*)alloc((size_t)NEDGE * 4);
  int* eidx    = (int*)alloc((size_t)NEDGE * 4);
  int* cnt     = (int*)alloc((size_t)NMAX * 4);
  int* col_ptr = (int*)alloc((size_t)(NMAX + 1) * 4);
  int* cursor  = (int*)alloc((size_t)NMAX * 4);
  float* dinv  = (float*)alloc((size_t)NMAX * 4);
  int* part    = (int*)alloc(256 * 4);
  int* newid   = (int*)alloc((size_t)NMAX * 4);
  float* score = (float*)alloc((size_t)NMAX * 4);
  int* sel     = (int*)alloc((size_t)BG * 512 * 4);
  float* tanhv = (float*)alloc((size_t)BG * 512 * 4);
  float* pn    = (float*)alloc(256);
  float* zh    = (float*)alloc((size_t)NMAX * HDIM * 4);
  float* x1    = (float*)alloc((size_t)BG * 512 * HDIM * 4);
  float* x2    = (float*)alloc((size_t)BG * 256 * HDIM * 4);
  float* x3    = (float*)alloc((size_t)BG * 128 * HDIM * 4);

  hipMemsetAsync(d_out, 0, (size_t)out_size * 4, stream);
  pnorm_kernel<<<3, 128, 0, stream>>>(pm[0], pm[1], pm[2], pn);
  copy_edges_kernel<<<NEDGE / 256, 256, 0, stream>>>(erow, ecol, cur_row, cur_col);

  const float* xin = x0;
  float* xout[3] = {x1, x2, x3};
  int Ps[3] = {1024, 512, 256};

  for (int L = 0; L < 3; ++L) {
    int P = Ps[L];
    int K = P >> 1;
    int n = BG * P;
    int nb = n / 1024;

    hipMemsetAsync(cnt, 0, (size_t)n * 4, stream);
    count_kernel<<<NEDGE / 256, 256, 0, stream>>>(cur_col, cnt);
    dinv_kernel<<<n / 256, 256, 0, stream>>>(cnt, dinv);
    scan1_kernel<<<nb, 256, 0, stream>>>(cnt, part);
    scan2_kernel<<<1, 256, 0, stream>>>(part, nb);
    scan3_kernel<<<nb, 256, 0, stream>>>(cnt, part, col_ptr, cursor, n);
    fill_kernel<<<NEDGE / 256, 256, 0, stream>>>(cur_col, cursor, eidx);
    agg_kernel<<<n, 128, 0, stream>>>(xin, zh, cur_row, eidx, col_ptr, dinv);
    conv_kernel<<<n / 64, 256, 0, stream>>>(zh, Wm[L], bm[L], pm[L], score);
    hipMemsetAsync(newid, 0xFF, (size_t)n * 4, stream);
    topk_kernel<<<BG, 256, 0, stream>>>(score, pn + L, sel, tanhv, newid, P, K);
    gather_kernel<<<BG * K, 128, 0, stream>>>(zh, sel, tanhv, xout[L]);
    readout_kernel<<<BG, 128, 0, stream>>>(xout[L], (float*)d_out, K);
    if (L < 2) relabel_kernel<<<NEDGE / 256, 256, 0, stream>>>(cur_row, cur_col, newid);
    xin = xout[L];
  }
}

// Round 2
// 822.184 us; speedup vs baseline: 1.1736x; 1.1736x over previous
//
#include <hip/hip_runtime.h>
#include <math.h>

#define BG   128            // graphs
#define NPER 1024           // nodes per graph, level 0
#define HDIM 128            // hidden
#define NEDGE (BG * NPER * 8)
#define NMAX (BG * NPER)    // 131072
#define CAP  48             // per-node edge bucket capacity (Poisson(8) tail ~1e-15)

// ---------------------------------------------------------------------------
// p-norms for the three pooling vectors
// ---------------------------------------------------------------------------

__global__ __launch_bounds__(128) void pnorm_kernel(
    const float* __restrict__ p1, const float* __restrict__ p2,
    const float* __restrict__ p3, float* __restrict__ pn) {
  const float* p = blockIdx.x == 0 ? p1 : (blockIdx.x == 1 ? p2 : p3);
  __shared__ float red[128];
  int t = threadIdx.x;
  float v = p[t];
  red[t] = v * v;
  __syncthreads();
  for (int off = 64; off; off >>= 1) {
    if (t < off) red[t] += red[t + off];
    __syncthreads();
  }
  if (t == 0) pn[blockIdx.x] = sqrtf(red[0]);
}

// ---------------------------------------------------------------------------
// L0: copy edges into mutable arrays + count in-degree (cnt must be zeroed)
// ---------------------------------------------------------------------------

__global__ __launch_bounds__(256) void copy_count_kernel(
    const int* __restrict__ er, const int* __restrict__ ec,
    int* __restrict__ cr, int* __restrict__ cc, int* __restrict__ cnt) {
  int e = blockIdx.x * 256 + threadIdx.x;
  int r = er[e], c = ec[e];
  cr[e] = r;
  cc[e] = c;
  atomicAdd(&cnt[c], 1);
}

// ---------------------------------------------------------------------------
// prep: dinv from counts; zero fill-cursor; init newid = -1
// ---------------------------------------------------------------------------

__global__ __launch_bounds__(256) void prep_kernel(
    const int* __restrict__ cnt, float* __restrict__ dinv,
    int* __restrict__ cursor, int* __restrict__ newid) {
  int i = blockIdx.x * 256 + threadIdx.x;
  dinv[i] = rsqrtf((float)cnt[i] + 1.0f);
  cursor[i] = 0;
  newid[i] = -1;
}

// ---------------------------------------------------------------------------
// fill: bucket CSR with src row + precomputed coefficient (no indirection left)
// ---------------------------------------------------------------------------

__global__ __launch_bounds__(256) void fill_kernel(
    const int* __restrict__ cr, const int* __restrict__ cc,
    const float* __restrict__ dinv, int* __restrict__ cursor,
    int* __restrict__ src, float* __restrict__ coef) {
  int e = blockIdx.x * 256 + threadIdx.x;
  int c = cc[e];
  if (c >= 0) {
    int r = cr[e];
    int pos = atomicAdd(&cursor[c], 1);
    if (pos < CAP) {
      src[(size_t)c * CAP + pos] = r;
      coef[(size_t)c * CAP + pos] = dinv[r] * dinv[c];
    }
  }
}

// ---------------------------------------------------------------------------
// aggregation: z[c] = sum_e x[src_e]*coef_e + x[c]*dinv[c]^2
// one 128-thread block per destination node; thread t = channel t
// XCD swizzle: block b -> node (b&7)*(n/8)+(b>>3) so each XCD sees a
// contiguous 16-graph slice (512 KB/graph stays L2-resident)
// ---------------------------------------------------------------------------

__global__ __launch_bounds__(128) void agg_kernel(
    const float* __restrict__ x, float* __restrict__ z,
    const int* __restrict__ src, const float* __restrict__ coef,
    const int* __restrict__ deg, const float* __restrict__ dinv, int n) {
  int b = blockIdx.x;
  int c = (b & 7) * (n >> 3) + (b >> 3);
  int t = threadIdx.x;
  __shared__ int s_src[CAP];
  __shared__ float s_cf[CAP];
  int d = deg[c];
  if (d > CAP) d = CAP;
  if (t < d) {
    s_src[t] = src[(size_t)c * CAP + t];
    s_cf[t] = coef[(size_t)c * CAP + t];
  }
  float dc = dinv[c];
  float acc0 = x[(size_t)c * HDIM + t] * dc * dc;
  float acc1 = 0.f;
  __syncthreads();
  int e = 0;
  for (; e + 1 < d; e += 2) {
    acc0 = fmaf(x[(size_t)s_src[e] * HDIM + t], s_cf[e], acc0);
    acc1 = fmaf(x[(size_t)s_src[e + 1] * HDIM + t], s_cf[e + 1], acc1);
  }
  if (e < d) acc0 = fmaf(x[(size_t)s_src[e] * HDIM + t], s_cf[e], acc0);
  z[(size_t)c * HDIM + t] = acc0 + acc1;
}

// ---------------------------------------------------------------------------
// conv: h = relu(z @ W + b), in-place on zh; also score[row] = h . p
// tile: 64 rows x 128 cols, block 256
// ---------------------------------------------------------------------------

__global__ __launch_bounds__(256) void conv_kernel(
    float* __restrict__ zh, const float* __restrict__ W,
    const float* __restrict__ bias, const float* __restrict__ p,
    float* __restrict__ score) {
  __shared__ float sZ[64 * HDIM];
  int tid = threadIdx.x;
  size_t base = (size_t)blockIdx.x * 64 * HDIM;
  float4* sZ4 = (float4*)sZ;
  const float4* g4 = (const float4*)(zh + base);
  #pragma unroll
  for (int i = 0; i < 8; ++i) sZ4[i * 256 + tid] = g4[i * 256 + tid];
  __syncthreads();

  int col_t = tid & 31;
  int row_t = tid >> 5;
  int r0 = row_t * 8;
  const float4* W4 = (const float4*)W;

  float acc[8][4];
  #pragma unroll
  for (int r = 0; r < 8; ++r)
    #pragma unroll
    for (int c = 0; c < 4; ++c) acc[r][c] = 0.f;

  for (int k4 = 0; k4 < 32; ++k4) {
    float4 w0 = W4[(k4 * 4 + 0) * 32 + col_t];
    float4 w1 = W4[(k4 * 4 + 1) * 32 + col_t];
    float4 w2 = W4[(k4 * 4 + 2) * 32 + col_t];
    float4 w3 = W4[(k4 * 4 + 3) * 32 + col_t];
    #pragma unroll
    for (int r = 0; r < 8; ++r) {
      float4 zr = sZ4[(r0 + r) * 32 + k4];
      acc[r][0] = fmaf(zr.x, w0.x, acc[r][0]);
      acc[r][1] = fmaf(zr.x, w0.y, acc[r][1]);
      acc[r][2] = fmaf(zr.x, w0.z, acc[r][2]);
      acc[r][3] = fmaf(zr.x, w0.w, acc[r][3]);
      acc[r][0] = fmaf(zr.y, w1.x, acc[r][0]);
      acc[r][1] = fmaf(zr.y, w1.y, acc[r][1]);
      acc[r][2] = fmaf(zr.y, w1.z, acc[r][2]);
      acc[r][3] = fmaf(zr.y, w1.w, acc[r][3]);
      acc[r][0] = fmaf(zr.z, w2.x, acc[r][0]);
      acc[r][1] = fmaf(zr.z, w2.y, acc[r][1]);
      acc[r][2] = fmaf(zr.z, w2.z, acc[r][2]);
      acc[r][3] = fmaf(zr.z, w2.w, acc[r][3]);
      acc[r][0] = fmaf(zr.w, w3.x, acc[r][0]);
      acc[r][1] = fmaf(zr.w, w3.y, acc[r][1]);
      acc[r][2] = fmaf(zr.w, w3.z, acc[r][2]);
      acc[r][3] = fmaf(zr.w, w3.w, acc[r][3]);
    }
  }

  float4 bv = ((const float4*)bias)[col_t];
  float4 pv = ((const float4*)p)[col_t];
  float4* out4 = (float4*)(zh + base);
  #pragma unroll
  for (int r = 0; r < 8; ++r) {
    float hx = fmaxf(acc[r][0] + bv.x, 0.f);
    float hy = fmaxf(acc[r][1] + bv.y, 0.f);
    float hz = fmaxf(acc[r][2] + bv.z, 0.f);
    float hw = fmaxf(acc[r][3] + bv.w, 0.f);
    float part = hx * pv.x + hy * pv.y + hz * pv.z + hw * pv.w;
    #pragma unroll
    for (int sft = 1; sft < 32; sft <<= 1) part += __shfl_xor(part, sft);
    out4[(r0 + r) * 32 + col_t] = make_float4(hx, hy, hz, hw);
    if (col_t == 0) score[blockIdx.x * 64 + r0 + r] = part;
  }
}

// ---------------------------------------------------------------------------
// per-graph top-K (K = P/2) by bitonic sort, descending, tie-break lower index
// also zeroes cnt[0 .. BG*K) for the next layer's relabel_count
// ---------------------------------------------------------------------------

__global__ __launch_bounds__(256) void topk_kernel(
    const float* __restrict__ score, const float* __restrict__ pnorm,
    int* __restrict__ sel, float* __restrict__ tanhv, int* __restrict__ newid,
    int* __restrict__ cnt_next, int P, int K) {
  __shared__ float sv[1024];
  __shared__ int si[1024];
  int g = blockIdx.x;
  int t = threadIdx.x;
  for (int j = t; j < K; j += 256) cnt_next[g * K + j] = 0;
  for (int i = t; i < P; i += 256) {
    sv[i] = score[(size_t)g * P + i];
    si[i] = i;
  }
  for (int size = 2; size <= P; size <<= 1) {
    for (int stride = size >> 1; stride; stride >>= 1) {
      __syncthreads();
      for (int i = t; i < P; i += 256) {
        int j = i ^ stride;
        if (j > i) {
          float a = sv[i], b = sv[j];
          int ia = si[i], ib = si[j];
          bool tFirst = (a > b) || (a == b && ia < ib);
          bool up = ((i & size) == 0);
          if (up ? !tFirst : tFirst) {
            sv[i] = b; sv[j] = a;
            si[i] = ib; si[j] = ia;
          }
        }
      }
    }
  }
  __syncthreads();
  float pn = pnorm[0];
  for (int j = t; j < K; j += 256) {
    float v = sv[j];
    int oldg = g * P + si[j];
    int newg = g * K + j;
    sel[newg] = oldg;
    tanhv[newg] = tanhf(v / pn);
    newid[oldg] = newg;
  }
}

// ---------------------------------------------------------------------------
// fused gather (x' = h[sel]*tanh) + readout (max / mean accumulate into out)
// block = graph; thread t: channel t&127, half t>>7 covers K/2 rows
// ---------------------------------------------------------------------------

__global__ __launch_bounds__(256) void pool_out_kernel(
    const float* __restrict__ h, const int* __restrict__ sel,
    const float* __restrict__ tanhv, float* __restrict__ xo,
    float* __restrict__ out, int K) {
  __shared__ float smx[256], ssm[256];
  int g = blockIdx.x;
  int t = threadIdx.x;
  int ch = t & 127, half = t >> 7;
  int j0 = half * (K >> 1), j1 = j0 + (K >> 1);
  float mx = -INFINITY, sm = 0.f;
  for (int j = j0; j < j1; ++j) {
    int idx = g * K + j;
    int s = sel[idx];
    float v = h[(size_t)s * HDIM + ch] * tanhv[idx];
    xo[(size_t)idx * HDIM + ch] = v;
    mx = fmaxf(mx, v);
    sm += v;
  }
  smx[t] = mx;
  ssm[t] = sm;
  __syncthreads();
  if (half == 0) {
    mx = fmaxf(smx[t], smx[t + 128]);
    sm = ssm[t] + ssm[t + 128];
    out[g * 256 + ch] += mx;
    out[g * 256 + 128 + ch] += sm / (float)K;
  }
}

// ---------------------------------------------------------------------------
// fused relabel + count for next layer (cnt_next zeroed by topk)
// ---------------------------------------------------------------------------

__global__ __launch_bounds__(256) void relabel_count_kernel(
    int* __restrict__ cr, int* __restrict__ cc,
    const int* __restrict__ newid, int* __restrict__ cnt) {
  int e = blockIdx.x * 256 + threadIdx.x;
  int r = cr[e];
  if (r < 0) return;
  int nr = newid[r];
  int nc = newid[cc[e]];
  if (nr < 0 || nc < 0) {
    cr[e] = -1;
    cc[e] = -1;
  } else {
    cr[e] = nr;
    cc[e] = nc;
    atomicAdd(&cnt[nc], 1);
  }
}

// ---------------------------------------------------------------------------
// launch
// ---------------------------------------------------------------------------

extern "C" void kernel_launch(void* const* d_in, const int* in_sizes, int n_in,
                              void* d_out, int out_size, void* d_ws, size_t ws_size,
                              hipStream_t stream) {
  const float* x0 = (const float*)d_in[0];
  const int* erow = (const int*)d_in[1];
  const int* ecol = (const int*)d_in[2];
  const float* Wm[3] = {(const float*)d_in[3], (const float*)d_in[6], (const float*)d_in[9]};
  const float* bm[3] = {(const float*)d_in[4], (const float*)d_in[7], (const float*)d_in[10]};
  const float* pm[3] = {(const float*)d_in[5], (const float*)d_in[8], (const float*)d_in[11]};

  char* w = (char*)d_ws;
  size_t off = 0;
  auto alloc = [&](size_t bytes) -> void* {
    void* ptr = w + off;
    off = (off + bytes + 255) & ~(size_t)255;
    return ptr;
  };
  int* cur_row = (int*)alloc((size_t)NEDGE * 4);
  int* cur_col = (int*)alloc((size_t)NEDGE * 4);
  int* src     = (int*)alloc((size_t)NMAX * CAP * 4);
  float* coef  = (float*)alloc((size_t)NMAX * CAP * 4);
  int* cnt     = (int*)alloc((size_t)NMAX * 4);
  int* cursor  = (int*)alloc((size_t)NMAX * 4);
  float* dinv  = (float*)alloc((size_t)NMAX * 4);
  int* newid   = (int*)alloc((size_t)NMAX * 4);
  float* score = (float*)alloc((size_t)NMAX * 4);
  int* sel     = (int*)alloc((size_t)BG * 512 * 4);
  float* tanhv = (float*)alloc((size_t)BG * 512 * 4);
  float* pn    = (float*)alloc(256);
  float* zh    = (float*)alloc((size_t)NMAX * HDIM * 4);
  float* x1    = (float*)alloc((size_t)BG * 512 * HDIM * 4);
  float* x2    = (float*)alloc((size_t)BG * 256 * HDIM * 4);
  float* x3    = (float*)alloc((size_t)BG * 128 * HDIM * 4);

  hipMemsetAsync(d_out, 0, (size_t)out_size * 4, stream);
  hipMemsetAsync(cnt, 0, (size_t)NMAX * 4, stream);
  pnorm_kernel<<<3, 128, 0, stream>>>(pm[0], pm[1], pm[2], pn);
  copy_count_kernel<<<NEDGE / 256, 256, 0, stream>>>(erow, ecol, cur_row, cur_col, cnt);

  const float* xin = x0;
  float* xout[3] = {x1, x2, x3};
  int Ps[3] = {1024, 512, 256};

  for (int L = 0; L < 3; ++L) {
    int P = Ps[L];
    int K = P >> 1;
    int n = BG * P;

    prep_kernel<<<n / 256, 256, 0, stream>>>(cnt, dinv, cursor, newid);
    fill_kernel<<<NEDGE / 256, 256, 0, stream>>>(cur_row, cur_col, dinv, cursor, src, coef);
    agg_kernel<<<n, 128, 0, stream>>>(xin, zh, src, coef, cursor, dinv, n);
    conv_kernel<<<n / 64, 256, 0, stream>>>(zh, Wm[L], bm[L], pm[L], score);
    topk_kernel<<<BG, 256, 0, stream>>>(score, pn + L, sel, tanhv, newid, cnt, P, K);
    pool_out_kernel<<<BG, 256, 0, stream>>>(zh, sel, tanhv, xout[L], (float*)d_out, K);
    if (L < 2) relabel_count_kernel<<<NEDGE / 256, 256, 0, stream>>>(cur_row, cur_col, newid, cnt);
    xin = xout[L];
  }
}

// Round 3
// 645.304 us; speedup vs baseline: 1.4953x; 1.2741x over previous
//
#include <hip/hip_runtime.h>
#include <math.h>

#define BG   128            // graphs
#define NPER 1024           // nodes per graph, level 0
#define HDIM 128            // hidden
#define NEDGE (BG * NPER * 8)
#define NMAX (BG * NPER)    // 131072
#define CAP  48             // per-node edge bucket capacity (Poisson(8) tail ~1e-15)

// ---------------------------------------------------------------------------
// p-norms for the three pooling vectors
// ---------------------------------------------------------------------------

__global__ __launch_bounds__(128) void pnorm_kernel(
    const float* __restrict__ p1, const float* __restrict__ p2,
    const float* __restrict__ p3, float* __restrict__ pn) {
  const float* p = blockIdx.x == 0 ? p1 : (blockIdx.x == 1 ? p2 : p3);
  __shared__ float red[128];
  int t = threadIdx.x;
  float v = p[t];
  red[t] = v * v;
  __syncthreads();
  for (int off = 64; off; off >>= 1) {
    if (t < off) red[t] += red[t + off];
    __syncthreads();
  }
  if (t == 0) pn[blockIdx.x] = sqrtf(red[0]);
}

// ---------------------------------------------------------------------------
// L0: copy edges into mutable arrays + count in-degree (cnt must be zeroed)
// ---------------------------------------------------------------------------

__global__ __launch_bounds__(256) void copy_count_kernel(
    const int* __restrict__ er, const int* __restrict__ ec,
    int* __restrict__ cr, int* __restrict__ cc, int* __restrict__ cnt) {
  int e = blockIdx.x * 256 + threadIdx.x;
  int r = er[e], c = ec[e];
  cr[e] = r;
  cc[e] = c;
  atomicAdd(&cnt[c], 1);
}

// ---------------------------------------------------------------------------
// prep: dinv from counts; zero fill-cursor; init newid = -1
// ---------------------------------------------------------------------------

__global__ __launch_bounds__(256) void prep_kernel(
    const int* __restrict__ cnt, float* __restrict__ dinv,
    int* __restrict__ cursor, int* __restrict__ newid) {
  int i = blockIdx.x * 256 + threadIdx.x;
  dinv[i] = rsqrtf((float)cnt[i] + 1.0f);
  cursor[i] = 0;
  newid[i] = -1;
}

// ---------------------------------------------------------------------------
// fill: bucket CSR with src row + precomputed coefficient (no indirection left)
// ---------------------------------------------------------------------------

__global__ __launch_bounds__(256) void fill_kernel(
    const int* __restrict__ cr, const int* __restrict__ cc,
    const float* __restrict__ dinv, int* __restrict__ cursor,
    int* __restrict__ src, float* __restrict__ coef) {
  int e = blockIdx.x * 256 + threadIdx.x;
  int c = cc[e];
  if (c >= 0) {
    int r = cr[e];
    int pos = atomicAdd(&cursor[c], 1);
    if (pos < CAP) {
      src[(size_t)c * CAP + pos] = r;
      coef[(size_t)c * CAP + pos] = dinv[r] * dinv[c];
    }
  }
}

// ---------------------------------------------------------------------------
// aggregation: z[c] = sum_e x[src_e]*coef_e + x[c]*dinv[c]^2
// one 128-thread block per destination node; thread t = channel t
// XCD swizzle: block b -> node (b&7)*(n/8)+(b>>3) so each XCD sees a
// contiguous 16-graph slice (512 KB/graph stays L2-resident)
// ---------------------------------------------------------------------------

__global__ __launch_bounds__(128) void agg_kernel(
    const float* __restrict__ x, float* __restrict__ z,
    const int* __restrict__ src, const float* __restrict__ coef,
    const int* __restrict__ deg, const float* __restrict__ dinv, int n) {
  int b = blockIdx.x;
  int c = (b & 7) * (n >> 3) + (b >> 3);
  int t = threadIdx.x;
  __shared__ int s_src[CAP];
  __shared__ float s_cf[CAP];
  int d = deg[c];
  if (d > CAP) d = CAP;
  if (t < d) {
    s_src[t] = src[(size_t)c * CAP + t];
    s_cf[t] = coef[(size_t)c * CAP + t];
  }
  float dc = dinv[c];
  float acc0 = x[(size_t)c * HDIM + t] * dc * dc;
  float acc1 = 0.f;
  __syncthreads();
  int e = 0;
  for (; e + 1 < d; e += 2) {
    acc0 = fmaf(x[(size_t)s_src[e] * HDIM + t], s_cf[e], acc0);
    acc1 = fmaf(x[(size_t)s_src[e + 1] * HDIM + t], s_cf[e + 1], acc1);
  }
  if (e < d) acc0 = fmaf(x[(size_t)s_src[e] * HDIM + t], s_cf[e], acc0);
  z[(size_t)c * HDIM + t] = acc0 + acc1;
}

// ---------------------------------------------------------------------------
// conv: h = relu(z @ W + b), in-place on zh; also score[row] = h . p
// tile: 64 rows x 128 cols, block 256
// ---------------------------------------------------------------------------

__global__ __launch_bounds__(256) void conv_kernel(
    float* __restrict__ zh, const float* __restrict__ W,
    const float* __restrict__ bias, const float* __restrict__ p,
    float* __restrict__ score) {
  __shared__ float sZ[64 * HDIM];
  int tid = threadIdx.x;
  size_t base = (size_t)blockIdx.x * 64 * HDIM;
  float4* sZ4 = (float4*)sZ;
  const float4* g4 = (const float4*)(zh + base);
  #pragma unroll
  for (int i = 0; i < 8; ++i) sZ4[i * 256 + tid] = g4[i * 256 + tid];
  __syncthreads();

  int col_t = tid & 31;
  int row_t = tid >> 5;
  int r0 = row_t * 8;
  const float4* W4 = (const float4*)W;

  float acc[8][4];
  #pragma unroll
  for (int r = 0; r < 8; ++r)
    #pragma unroll
    for (int c = 0; c < 4; ++c) acc[r][c] = 0.f;

  for (int k4 = 0; k4 < 32; ++k4) {
    float4 w0 = W4[(k4 * 4 + 0) * 32 + col_t];
    float4 w1 = W4[(k4 * 4 + 1) * 32 + col_t];
    float4 w2 = W4[(k4 * 4 + 2) * 32 + col_t];
    float4 w3 = W4[(k4 * 4 + 3) * 32 + col_t];
    #pragma unroll
    for (int r = 0; r < 8; ++r) {
      float4 zr = sZ4[(r0 + r) * 32 + k4];
      acc[r][0] = fmaf(zr.x, w0.x, acc[r][0]);
      acc[r][1] = fmaf(zr.x, w0.y, acc[r][1]);
      acc[r][2] = fmaf(zr.x, w0.z, acc[r][2]);
      acc[r][3] = fmaf(zr.x, w0.w, acc[r][3]);
      acc[r][0] = fmaf(zr.y, w1.x, acc[r][0]);
      acc[r][1] = fmaf(zr.y, w1.y, acc[r][1]);
      acc[r][2] = fmaf(zr.y, w1.z, acc[r][2]);
      acc[r][3] = fmaf(zr.y, w1.w, acc[r][3]);
      acc[r][0] = fmaf(zr.z, w2.x, acc[r][0]);
      acc[r][1] = fmaf(zr.z, w2.y, acc[r][1]);
      acc[r][2] = fmaf(zr.z, w2.z, acc[r][2]);
      acc[r][3] = fmaf(zr.z, w2.w, acc[r][3]);
      acc[r][0] = fmaf(zr.w, w3.x, acc[r][0]);
      acc[r][1] = fmaf(zr.w, w3.y, acc[r][1]);
      acc[r][2] = fmaf(zr.w, w3.z, acc[r][2]);
      acc[r][3] = fmaf(zr.w, w3.w, acc[r][3]);
    }
  }

  float4 bv = ((const float4*)bias)[col_t];
  float4 pv = ((const float4*)p)[col_t];
  float4* out4 = (float4*)(zh + base);
  #pragma unroll
  for (int r = 0; r < 8; ++r) {
    float hx = fmaxf(acc[r][0] + bv.x, 0.f);
    float hy = fmaxf(acc[r][1] + bv.y, 0.f);
    float hz = fmaxf(acc[r][2] + bv.z, 0.f);
    float hw = fmaxf(acc[r][3] + bv.w, 0.f);
    float part = hx * pv.x + hy * pv.y + hz * pv.z + hw * pv.w;
    #pragma unroll
    for (int sft = 1; sft < 32; sft <<= 1) part += __shfl_xor(part, sft);
    out4[(r0 + r) * 32 + col_t] = make_float4(hx, hy, hz, hw);
    if (col_t == 0) score[blockIdx.x * 64 + r0 + r] = part;
  }
}

// ---------------------------------------------------------------------------
// per-graph top-K (K = P/2) by bitonic sort, descending, tie-break lower index
// also zeroes cnt[0 .. BG*K) for the next layer's relabel_count
// ---------------------------------------------------------------------------

__global__ __launch_bounds__(256) void topk_kernel(
    const float* __restrict__ score, const float* __restrict__ pnorm,
    int* __restrict__ sel, float* __restrict__ tanhv, int* __restrict__ newid,
    int* __restrict__ cnt_next, int P, int K) {
  __shared__ float sv[1024];
  __shared__ int si[1024];
  int g = blockIdx.x;
  int t = threadIdx.x;
  for (int j = t; j < K; j += 256) cnt_next[g * K + j] = 0;
  for (int i = t; i < P; i += 256) {
    sv[i] = score[(size_t)g * P + i];
    si[i] = i;
  }
  for (int size = 2; size <= P; size <<= 1) {
    for (int stride = size >> 1; stride; stride >>= 1) {
      __syncthreads();
      for (int i = t; i < P; i += 256) {
        int j = i ^ stride;
        if (j > i) {
          float a = sv[i], b = sv[j];
          int ia = si[i], ib = si[j];
          bool tFirst = (a > b) || (a == b && ia < ib);
          bool up = ((i & size) == 0);
          if (up ? !tFirst : tFirst) {
            sv[i] = b; sv[j] = a;
            si[i] = ib; si[j] = ia;
          }
        }
      }
    }
  }
  __syncthreads();
  float pn = pnorm[0];
  for (int j = t; j < K; j += 256) {
    float v = sv[j];
    int oldg = g * P + si[j];
    int newg = g * K + j;
    sel[newg] = oldg;
    tanhv[newg] = tanhf(v / pn);
    newid[oldg] = newg;
  }
}

// ---------------------------------------------------------------------------
// pool gather: xo[j] = h[sel[j]] * tanhv[j] for a 16-row chunk; emit per-chunk
// partial max/sum.  grid = BG * (K/16); block 256: ch = t&127, half = t>>7
// sel/tanh prefetched to LDS -> no dependent gather chain
// ---------------------------------------------------------------------------

__global__ __launch_bounds__(256) void pool_gather_kernel(
    const float* __restrict__ h, const int* __restrict__ sel,
    const float* __restrict__ tanhv, float* __restrict__ xo,
    float* __restrict__ pred, int K, int lc) {
  __shared__ int s_sel[16];
  __shared__ float s_th[16];
  __shared__ float smx[256], ssm[256];
  int b = blockIdx.x;
  int g = b >> lc;
  int chunk = b & ((1 << lc) - 1);
  int t = threadIdx.x;
  int j0 = chunk * 16;
  if (t < 16) {
    s_sel[t] = sel[g * K + j0 + t];
    s_th[t] = tanhv[g * K + j0 + t];
  }
  __syncthreads();
  int ch = t & 127, half = t >> 7;
  float mx = -INFINITY, sm = 0.f;
  #pragma unroll
  for (int i = 0; i < 8; ++i) {
    int j = half * 8 + i;
    float v = h[(size_t)s_sel[j] * HDIM + ch] * s_th[j];
    xo[(size_t)(g * K + j0 + j) * HDIM + ch] = v;
    mx = fmaxf(mx, v);
    sm += v;
  }
  smx[t] = mx;
  ssm[t] = sm;
  __syncthreads();
  if (half == 0) {
    mx = fmaxf(smx[t], smx[t + 128]);
    sm = ssm[t] + ssm[t + 128];
    pred[(size_t)(g * 32 + chunk) * 256 + ch] = mx;
    pred[(size_t)(g * 32 + chunk) * 256 + 128 + ch] = sm;
  }
}

// ---------------------------------------------------------------------------
// pool combine: reduce C chunk-partials per graph, accumulate into out
// ---------------------------------------------------------------------------

__global__ __launch_bounds__(256) void pool_combine_kernel(
    const float* __restrict__ pred, float* __restrict__ out, int K, int C) {
  int g = blockIdx.x;
  int t = threadIdx.x;
  int ch = t & 127, half = t >> 7;
  if (half == 0) {
    float mx = -INFINITY;
    for (int c = 0; c < C; ++c)
      mx = fmaxf(mx, pred[(size_t)(g * 32 + c) * 256 + ch]);
    out[g * 256 + ch] += mx;
  } else {
    float sm = 0.f;
    for (int c = 0; c < C; ++c)
      sm += pred[(size_t)(g * 32 + c) * 256 + 128 + ch];
    out[g * 256 + 128 + ch] += sm / (float)K;
  }
}

// ---------------------------------------------------------------------------
// fused relabel + count for next layer (cnt_next zeroed by topk)
// ---------------------------------------------------------------------------

__global__ __launch_bounds__(256) void relabel_count_kernel(
    int* __restrict__ cr, int* __restrict__ cc,
    const int* __restrict__ newid, int* __restrict__ cnt) {
  int e = blockIdx.x * 256 + threadIdx.x;
  int r = cr[e];
  if (r < 0) return;
  int nr = newid[r];
  int nc = newid[cc[e]];
  if (nr < 0 || nc < 0) {
    cr[e] = -1;
    cc[e] = -1;
  } else {
    cr[e] = nr;
    cc[e] = nc;
    atomicAdd(&cnt[nc], 1);
  }
}

// ---------------------------------------------------------------------------
// launch
// ---------------------------------------------------------------------------

extern "C" void kernel_launch(void* const* d_in, const int* in_sizes, int n_in,
                              void* d_out, int out_size, void* d_ws, size_t ws_size,
                              hipStream_t stream) {
  const float* x0 = (const float*)d_in[0];
  const int* erow = (const int*)d_in[1];
  const int* ecol = (const int*)d_in[2];
  const float* Wm[3] = {(const float*)d_in[3], (const float*)d_in[6], (const float*)d_in[9]};
  const float* bm[3] = {(const float*)d_in[4], (const float*)d_in[7], (const float*)d_in[10]};
  const float* pm[3] = {(const float*)d_in[5], (const float*)d_in[8], (const float*)d_in[11]};

  char* w = (char*)d_ws;
  size_t off = 0;
  auto alloc = [&](size_t bytes) -> void* {
    void* ptr = w + off;
    off = (off + bytes + 255) & ~(size_t)255;
    return ptr;
  };
  int* cur_row = (int*)alloc((size_t)NEDGE * 4);
  int* cur_col = (int*)alloc((size_t)NEDGE * 4);
  int* src     = (int*)alloc((size_t)NMAX * CAP * 4);
  float* coef  = (float*)alloc((size_t)NMAX * CAP * 4);
  int* cnt     = (int*)alloc((size_t)NMAX * 4);
  int* cursor  = (int*)alloc((size_t)NMAX * 4);
  float* dinv  = (float*)alloc((size_t)NMAX * 4);
  int* newid   = (int*)alloc((size_t)NMAX * 4);
  float* score = (float*)alloc((size_t)NMAX * 4);
  int* sel     = (int*)alloc((size_t)BG * 512 * 4);
  float* tanhv = (float*)alloc((size_t)BG * 512 * 4);
  float* pn    = (float*)alloc(256);
  float* pred  = (float*)alloc((size_t)BG * 32 * 256 * 4);
  float* zh    = (float*)alloc((size_t)NMAX * HDIM * 4);
  float* x1    = (float*)alloc((size_t)BG * 512 * HDIM * 4);
  float* x2    = (float*)alloc((size_t)BG * 256 * HDIM * 4);
  float* x3    = (float*)alloc((size_t)BG * 128 * HDIM * 4);

  hipMemsetAsync(d_out, 0, (size_t)out_size * 4, stream);
  hipMemsetAsync(cnt, 0, (size_t)NMAX * 4, stream);
  pnorm_kernel<<<3, 128, 0, stream>>>(pm[0], pm[1], pm[2], pn);
  copy_count_kernel<<<NEDGE / 256, 256, 0, stream>>>(erow, ecol, cur_row, cur_col, cnt);

  const float* xin = x0;
  float* xout[3] = {x1, x2, x3};
  int Ps[3] = {1024, 512, 256};
  int LCs[3] = {5, 4, 3};     // log2(K/16)

  for (int L = 0; L < 3; ++L) {
    int P = Ps[L];
    int K = P >> 1;
    int n = BG * P;
    int lc = LCs[L];
    int C = 1 << lc;

    prep_kernel<<<n / 256, 256, 0, stream>>>(cnt, dinv, cursor, newid);
    fill_kernel<<<NEDGE / 256, 256, 0, stream>>>(cur_row, cur_col, dinv, cursor, src, coef);
    agg_kernel<<<n, 128, 0, stream>>>(xin, zh, src, coef, cursor, dinv, n);
    conv_kernel<<<n / 64, 256, 0, stream>>>(zh, Wm[L], bm[L], pm[L], score);
    topk_kernel<<<BG, 256, 0, stream>>>(score, pn + L, sel, tanhv, newid, cnt, P, K);
    pool_gather_kernel<<<BG * C, 256, 0, stream>>>(zh, sel, tanhv, xout[L], pred, K, lc);
    pool_combine_kernel<<<BG, 256, 0, stream>>>(pred, (float*)d_out, K, C);
    if (L < 2) relabel_count_kernel<<<NEDGE / 256, 256, 0, stream>>>(cur_row, cur_col, newid, cnt);
    xin = xout[L];
  }
}

// Round 4
// 586.412 us; speedup vs baseline: 1.6455x; 1.1004x over previous
//
#include <hip/hip_runtime.h>
#include <math.h>

#define BG   128            // graphs
#define NPER 1024           // nodes per graph, level 0
#define HDIM 128            // hidden
#define NEDGE (BG * NPER * 8)
#define NMAX (BG * NPER)    // 131072
#define CAP  48             // per-node edge bucket capacity (Poisson(8) tail ~1e-15)
#define PRE  16             // LDS-prefetched edges per node (P(deg>16) ~ 0.4%)

// ---------------------------------------------------------------------------
// p-norms for the three pooling vectors
// ---------------------------------------------------------------------------

__global__ __launch_bounds__(128) void pnorm_kernel(
    const float* __restrict__ p1, const float* __restrict__ p2,
    const float* __restrict__ p3, float* __restrict__ pn) {
  const float* p = blockIdx.x == 0 ? p1 : (blockIdx.x == 1 ? p2 : p3);
  __shared__ float red[128];
  int t = threadIdx.x;
  float v = p[t];
  red[t] = v * v;
  __syncthreads();
  for (int off = 64; off; off >>= 1) {
    if (t < off) red[t] += red[t + off];
    __syncthreads();
  }
  if (t == 0) pn[blockIdx.x] = sqrtf(red[0]);
}

// ---------------------------------------------------------------------------
// L0: copy edges into mutable arrays + count in-degree (cnt must be zeroed)
// ---------------------------------------------------------------------------

__global__ __launch_bounds__(256) void copy_count_kernel(
    const int* __restrict__ er, const int* __restrict__ ec,
    int* __restrict__ cr, int* __restrict__ cc, int* __restrict__ cnt) {
  int e = blockIdx.x * 256 + threadIdx.x;
  int r = er[e], c = ec[e];
  cr[e] = r;
  cc[e] = c;
  atomicAdd(&cnt[c], 1);
}

// ---------------------------------------------------------------------------
// prep: dinv from counts; zero fill-cursor; init newid = -1
// ---------------------------------------------------------------------------

__global__ __launch_bounds__(256) void prep_kernel(
    const int* __restrict__ cnt, float* __restrict__ dinv,
    int* __restrict__ cursor, int* __restrict__ newid) {
  int i = blockIdx.x * 256 + threadIdx.x;
  dinv[i] = rsqrtf((float)cnt[i] + 1.0f);
  cursor[i] = 0;
  newid[i] = -1;
}

// ---------------------------------------------------------------------------
// fill: bucket CSR with src row + precomputed coefficient (no indirection left)
// ---------------------------------------------------------------------------

__global__ __launch_bounds__(256) void fill_kernel(
    const int* __restrict__ cr, const int* __restrict__ cc,
    const float* __restrict__ dinv, int* __restrict__ cursor,
    int* __restrict__ src, float* __restrict__ coef) {
  int e = blockIdx.x * 256 + threadIdx.x;
  int c = cc[e];
  if (c >= 0) {
    int r = cr[e];
    int pos = atomicAdd(&cursor[c], 1);
    if (pos < CAP) {
      src[(size_t)c * CAP + pos] = r;
      coef[(size_t)c * CAP + pos] = dinv[r] * dinv[c];
    }
  }
}

// ---------------------------------------------------------------------------
// aggregation: z[c] = sum_e x[src_e]*coef_e + x[c]*dinv[c]^2
// block of 256 = 8 nodes; thread: node = t>>5, lane = t&31 -> channels 4*lane
// float4 gathers: one 512 B row per 32-lane group (16 B/lane sweet spot)
// XCD swizzle keeps each XCD's gather working set to a contiguous graph slice
// ---------------------------------------------------------------------------

__global__ __launch_bounds__(256) void agg_kernel(
    const float* __restrict__ x, float* __restrict__ z,
    const int* __restrict__ src, const float* __restrict__ coef,
    const int* __restrict__ deg, const float* __restrict__ dinv, int n) {
  int nb = n >> 3;                              // node-octet blocks
  int b = blockIdx.x;
  int blk = (b & 7) * (nb >> 3) + (b >> 3);     // XCD swizzle
  int c0 = blk * 8;
  int t = threadIdx.x;
  int node = t >> 5, lane = t & 31;
  int c = c0 + node;

  __shared__ int s_src[8][PRE];
  __shared__ float s_cf[8][PRE];
  if (t < 128) {
    int nd = t >> 4, e = t & 15;
    s_src[nd][e] = src[(size_t)(c0 + nd) * CAP + e];
    s_cf[nd][e] = coef[(size_t)(c0 + nd) * CAP + e];
  }

  int d = deg[c];
  if (d > CAP) d = CAP;
  float dc = dinv[c];
  float s = dc * dc;
  const float4* x4 = (const float4*)x;
  float4 xs = x4[(size_t)c * 32 + lane];
  float4 a0 = make_float4(xs.x * s, xs.y * s, xs.z * s, xs.w * s);
  float4 a1 = make_float4(0.f, 0.f, 0.f, 0.f);
  __syncthreads();

  int dp = d < PRE ? d : PRE;
  int e = 0;
  for (; e + 1 < dp; e += 2) {
    int r0 = s_src[node][e], r1 = s_src[node][e + 1];
    float f0 = s_cf[node][e], f1 = s_cf[node][e + 1];
    float4 v0 = x4[(size_t)r0 * 32 + lane];
    float4 v1 = x4[(size_t)r1 * 32 + lane];
    a0.x = fmaf(v0.x, f0, a0.x);
    a0.y = fmaf(v0.y, f0, a0.y);
    a0.z = fmaf(v0.z, f0, a0.z);
    a0.w = fmaf(v0.w, f0, a0.w);
    a1.x = fmaf(v1.x, f1, a1.x);
    a1.y = fmaf(v1.y, f1, a1.y);
    a1.z = fmaf(v1.z, f1, a1.z);
    a1.w = fmaf(v1.w, f1, a1.w);
  }
  if (e < dp) {
    int r0 = s_src[node][e];
    float f0 = s_cf[node][e];
    float4 v0 = x4[(size_t)r0 * 32 + lane];
    a0.x = fmaf(v0.x, f0, a0.x);
    a0.y = fmaf(v0.y, f0, a0.y);
    a0.z = fmaf(v0.z, f0, a0.z);
    a0.w = fmaf(v0.w, f0, a0.w);
  }
  for (e = PRE; e < d; ++e) {                   // rare tail (deg > 16)
    int r0 = src[(size_t)c * CAP + e];
    float f0 = coef[(size_t)c * CAP + e];
    float4 v0 = x4[(size_t)r0 * 32 + lane];
    a0.x = fmaf(v0.x, f0, a0.x);
    a0.y = fmaf(v0.y, f0, a0.y);
    a0.z = fmaf(v0.z, f0, a0.z);
    a0.w = fmaf(v0.w, f0, a0.w);
  }
  float4 o = make_float4(a0.x + a1.x, a0.y + a1.y, a0.z + a1.z, a0.w + a1.w);
  ((float4*)z)[(size_t)c * 32 + lane] = o;
}

// ---------------------------------------------------------------------------
// conv: h = relu(z @ W + b), in-place on zh; also score[row] = h . p
// tile: 64 rows x 128 cols, block 256
// ---------------------------------------------------------------------------

__global__ __launch_bounds__(256) void conv_kernel(
    float* __restrict__ zh, const float* __restrict__ W,
    const float* __restrict__ bias, const float* __restrict__ p,
    float* __restrict__ score) {
  __shared__ float sZ[64 * HDIM];
  int tid = threadIdx.x;
  size_t base = (size_t)blockIdx.x * 64 * HDIM;
  float4* sZ4 = (float4*)sZ;
  const float4* g4 = (const float4*)(zh + base);
  #pragma unroll
  for (int i = 0; i < 8; ++i) sZ4[i * 256 + tid] = g4[i * 256 + tid];
  __syncthreads();

  int col_t = tid & 31;
  int row_t = tid >> 5;
  int r0 = row_t * 8;
  const float4* W4 = (const float4*)W;

  float acc[8][4];
  #pragma unroll
  for (int r = 0; r < 8; ++r)
    #pragma unroll
    for (int c = 0; c < 4; ++c) acc[r][c] = 0.f;

  for (int k4 = 0; k4 < 32; ++k4) {
    float4 w0 = W4[(k4 * 4 + 0) * 32 + col_t];
    float4 w1 = W4[(k4 * 4 + 1) * 32 + col_t];
    float4 w2 = W4[(k4 * 4 + 2) * 32 + col_t];
    float4 w3 = W4[(k4 * 4 + 3) * 32 + col_t];
    #pragma unroll
    for (int r = 0; r < 8; ++r) {
      float4 zr = sZ4[(r0 + r) * 32 + k4];
      acc[r][0] = fmaf(zr.x, w0.x, acc[r][0]);
      acc[r][1] = fmaf(zr.x, w0.y, acc[r][1]);
      acc[r][2] = fmaf(zr.x, w0.z, acc[r][2]);
      acc[r][3] = fmaf(zr.x, w0.w, acc[r][3]);
      acc[r][0] = fmaf(zr.y, w1.x, acc[r][0]);
      acc[r][1] = fmaf(zr.y, w1.y, acc[r][1]);
      acc[r][2] = fmaf(zr.y, w1.z, acc[r][2]);
      acc[r][3] = fmaf(zr.y, w1.w, acc[r][3]);
      acc[r][0] = fmaf(zr.z, w2.x, acc[r][0]);
      acc[r][1] = fmaf(zr.z, w2.y, acc[r][1]);
      acc[r][2] = fmaf(zr.z, w2.z, acc[r][2]);
      acc[r][3] = fmaf(zr.z, w2.w, acc[r][3]);
      acc[r][0] = fmaf(zr.w, w3.x, acc[r][0]);
      acc[r][1] = fmaf(zr.w, w3.y, acc[r][1]);
      acc[r][2] = fmaf(zr.w, w3.z, acc[r][2]);
      acc[r][3] = fmaf(zr.w, w3.w, acc[r][3]);
    }
  }

  float4 bv = ((const float4*)bias)[col_t];
  float4 pv = ((const float4*)p)[col_t];
  float4* out4 = (float4*)(zh + base);
  #pragma unroll
  for (int r = 0; r < 8; ++r) {
    float hx = fmaxf(acc[r][0] + bv.x, 0.f);
    float hy = fmaxf(acc[r][1] + bv.y, 0.f);
    float hz = fmaxf(acc[r][2] + bv.z, 0.f);
    float hw = fmaxf(acc[r][3] + bv.w, 0.f);
    float part = hx * pv.x + hy * pv.y + hz * pv.z + hw * pv.w;
    #pragma unroll
    for (int sft = 1; sft < 32; sft <<= 1) part += __shfl_xor(part, sft);
    out4[(r0 + r) * 32 + col_t] = make_float4(hx, hy, hz, hw);
    if (col_t == 0) score[blockIdx.x * 64 + r0 + r] = part;
  }
}

// ---------------------------------------------------------------------------
// per-graph top-K (K = P/2) by bitonic sort, descending, tie-break lower index
// also zeroes cnt[0 .. BG*K) for the next layer's relabel_count
// ---------------------------------------------------------------------------

__global__ __launch_bounds__(256) void topk_kernel(
    const float* __restrict__ score, const float* __restrict__ pnorm,
    int* __restrict__ sel, float* __restrict__ tanhv, int* __restrict__ newid,
    int* __restrict__ cnt_next, int P, int K) {
  __shared__ float sv[1024];
  __shared__ int si[1024];
  int g = blockIdx.x;
  int t = threadIdx.x;
  for (int j = t; j < K; j += 256) cnt_next[g * K + j] = 0;
  for (int i = t; i < P; i += 256) {
    sv[i] = score[(size_t)g * P + i];
    si[i] = i;
  }
  for (int size = 2; size <= P; size <<= 1) {
    for (int stride = size >> 1; stride; stride >>= 1) {
      __syncthreads();
      for (int i = t; i < P; i += 256) {
        int j = i ^ stride;
        if (j > i) {
          float a = sv[i], b = sv[j];
          int ia = si[i], ib = si[j];
          bool tFirst = (a > b) || (a == b && ia < ib);
          bool up = ((i & size) == 0);
          if (up ? !tFirst : tFirst) {
            sv[i] = b; sv[j] = a;
            si[i] = ib; si[j] = ia;
          }
        }
      }
    }
  }
  __syncthreads();
  float pn = pnorm[0];
  for (int j = t; j < K; j += 256) {
    float v = sv[j];
    int oldg = g * P + si[j];
    int newg = g * K + j;
    sel[newg] = oldg;
    tanhv[newg] = tanhf(v / pn);
    newid[oldg] = newg;
  }
}

// ---------------------------------------------------------------------------
// pool gather: xo[j] = h[sel[j]] * tanhv[j] for a 16-row chunk; float4 lanes.
// grid = BG * (K/16); block 256: lane = t&31 -> channels 4*lane, slot = t>>5
// covers rows {slot, slot+8}; per-chunk partial max/sum to pred
// ---------------------------------------------------------------------------

__global__ __launch_bounds__(256) void pool_gather_kernel(
    const float* __restrict__ h, const int* __restrict__ sel,
    const float* __restrict__ tanhv, float* __restrict__ xo,
    float* __restrict__ pred, int K, int lc) {
  __shared__ int s_sel[16];
  __shared__ float s_th[16];
  __shared__ float4 smx[8][32], ssm[8][32];
  int b = blockIdx.x;
  int g = b >> lc;
  int chunk = b & ((1 << lc) - 1);
  int t = threadIdx.x;
  int j0 = chunk * 16;
  if (t < 16) {
    s_sel[t] = sel[g * K + j0 + t];
    s_th[t] = tanhv[g * K + j0 + t];
  }
  __syncthreads();
  int lane = t & 31, slot = t >> 5;
  const float4* h4 = (const float4*)h;
  float4* xo4 = (float4*)xo;
  float4 mx = make_float4(-INFINITY, -INFINITY, -INFINITY, -INFINITY);
  float4 sm = make_float4(0.f, 0.f, 0.f, 0.f);
  #pragma unroll
  for (int i = 0; i < 2; ++i) {
    int j = slot + i * 8;
    float th = s_th[j];
    float4 v = h4[(size_t)s_sel[j] * 32 + lane];
    v.x *= th; v.y *= th; v.z *= th; v.w *= th;
    xo4[(size_t)(g * K + j0 + j) * 32 + lane] = v;
    mx.x = fmaxf(mx.x, v.x); mx.y = fmaxf(mx.y, v.y);
    mx.z = fmaxf(mx.z, v.z); mx.w = fmaxf(mx.w, v.w);
    sm.x += v.x; sm.y += v.y; sm.z += v.z; sm.w += v.w;
  }
  smx[slot][lane] = mx;
  ssm[slot][lane] = sm;
  __syncthreads();
  if (slot == 0) {
    #pragma unroll
    for (int s2 = 1; s2 < 8; ++s2) {
      float4 m2 = smx[s2][lane], s3 = ssm[s2][lane];
      mx.x = fmaxf(mx.x, m2.x); mx.y = fmaxf(mx.y, m2.y);
      mx.z = fmaxf(mx.z, m2.z); mx.w = fmaxf(mx.w, m2.w);
      sm.x += s3.x; sm.y += s3.y; sm.z += s3.z; sm.w += s3.w;
    }
    float4* pred4 = (float4*)pred;
    pred4[(size_t)(g * 32 + chunk) * 64 + lane] = mx;
    pred4[(size_t)(g * 32 + chunk) * 64 + 32 + lane] = sm;
  }
}

// ---------------------------------------------------------------------------
// pool combine: reduce C chunk-partials per graph, accumulate into out
// block = 64 threads: t<32 -> max channels 4t.., t>=32 -> sum channels
// ---------------------------------------------------------------------------

__global__ __launch_bounds__(64) void pool_combine_kernel(
    const float* __restrict__ pred, float* __restrict__ out, int K, int C) {
  int g = blockIdx.x;
  int t = threadIdx.x;
  const float4* pred4 = (const float4*)pred;
  float4* out4 = (float4*)out;
  if (t < 32) {
    float4 mx = make_float4(-INFINITY, -INFINITY, -INFINITY, -INFINITY);
    for (int c = 0; c < C; ++c) {
      float4 v = pred4[(size_t)(g * 32 + c) * 64 + t];
      mx.x = fmaxf(mx.x, v.x); mx.y = fmaxf(mx.y, v.y);
      mx.z = fmaxf(mx.z, v.z); mx.w = fmaxf(mx.w, v.w);
    }
    float4 o = out4[g * 64 + t];
    o.x += mx.x; o.y += mx.y; o.z += mx.z; o.w += mx.w;
    out4[g * 64 + t] = o;
  } else {
    int l = t - 32;
    float4 sm = make_float4(0.f, 0.f, 0.f, 0.f);
    for (int c = 0; c < C; ++c) {
      float4 v = pred4[(size_t)(g * 32 + c) * 64 + 32 + l];
      sm.x += v.x; sm.y += v.y; sm.z += v.z; sm.w += v.w;
    }
    float inv = 1.0f / (float)K;
    float4 o = out4[g * 64 + 32 + l];
    o.x += sm.x * inv; o.y += sm.y * inv; o.z += sm.z * inv; o.w += sm.w * inv;
    out4[g * 64 + 32 + l] = o;
  }
}

// ---------------------------------------------------------------------------
// fused relabel + count for next layer (cnt_next zeroed by topk)
// ---------------------------------------------------------------------------

__global__ __launch_bounds__(256) void relabel_count_kernel(
    int* __restrict__ cr, int* __restrict__ cc,
    const int* __restrict__ newid, int* __restrict__ cnt) {
  int e = blockIdx.x * 256 + threadIdx.x;
  int r = cr[e];
  if (r < 0) return;
  int nr = newid[r];
  int nc = newid[cc[e]];
  if (nr < 0 || nc < 0) {
    cr[e] = -1;
    cc[e] = -1;
  } else {
    cr[e] = nr;
    cc[e] = nc;
    atomicAdd(&cnt[nc], 1);
  }
}

// ---------------------------------------------------------------------------
// launch
// ---------------------------------------------------------------------------

extern "C" void kernel_launch(void* const* d_in, const int* in_sizes, int n_in,
                              void* d_out, int out_size, void* d_ws, size_t ws_size,
                              hipStream_t stream) {
  const float* x0 = (const float*)d_in[0];
  const int* erow = (const int*)d_in[1];
  const int* ecol = (const int*)d_in[2];
  const float* Wm[3] = {(const float*)d_in[3], (const float*)d_in[6], (const float*)d_in[9]};
  const float* bm[3] = {(const float*)d_in[4], (const float*)d_in[7], (const float*)d_in[10]};
  const float* pm[3] = {(const float*)d_in[5], (const float*)d_in[8], (const float*)d_in[11]};

  char* w = (char*)d_ws;
  size_t off = 0;
  auto alloc = [&](size_t bytes) -> void* {
    void* ptr = w + off;
    off = (off + bytes + 255) & ~(size_t)255;
    return ptr;
  };
  int* cur_row = (int*)alloc((size_t)NEDGE * 4);
  int* cur_col = (int*)alloc((size_t)NEDGE * 4);
  int* src     = (int*)alloc((size_t)NMAX * CAP * 4);
  float* coef  = (float*)alloc((size_t)NMAX * CAP * 4);
  int* cnt     = (int*)alloc((size_t)NMAX * 4);
  int* cursor  = (int*)alloc((size_t)NMAX * 4);
  float* dinv  = (float*)alloc((size_t)NMAX * 4);
  int* newid   = (int*)alloc((size_t)NMAX * 4);
  float* score = (float*)alloc((size_t)NMAX * 4);
  int* sel     = (int*)alloc((size_t)BG * 512 * 4);
  float* tanhv = (float*)alloc((size_t)BG * 512 * 4);
  float* pn    = (float*)alloc(256);
  float* pred  = (float*)alloc((size_t)BG * 32 * 256 * 4);
  float* zh    = (float*)alloc((size_t)NMAX * HDIM * 4);
  float* x1    = (float*)alloc((size_t)BG * 512 * HDIM * 4);
  float* x2    = (float*)alloc((size_t)BG * 256 * HDIM * 4);
  float* x3    = (float*)alloc((size_t)BG * 128 * HDIM * 4);

  hipMemsetAsync(d_out, 0, (size_t)out_size * 4, stream);
  hipMemsetAsync(cnt, 0, (size_t)NMAX * 4, stream);
  pnorm_kernel<<<3, 128, 0, stream>>>(pm[0], pm[1], pm[2], pn);
  copy_count_kernel<<<NEDGE / 256, 256, 0, stream>>>(erow, ecol, cur_row, cur_col, cnt);

  const float* xin = x0;
  float* xout[3] = {x1, x2, x3};
  int Ps[3] = {1024, 512, 256};
  int LCs[3] = {5, 4, 3};     // log2(K/16)

  for (int L = 0; L < 3; ++L) {
    int P = Ps[L];
    int K = P >> 1;
    int n = BG * P;
    int lc = LCs[L];
    int C = 1 << lc;

    prep_kernel<<<n / 256, 256, 0, stream>>>(cnt, dinv, cursor, newid);
    fill_kernel<<<NEDGE / 256, 256, 0, stream>>>(cur_row, cur_col, dinv, cursor, src, coef);
    agg_kernel<<<n / 8, 256, 0, stream>>>(xin, zh, src, coef, cursor, dinv, n);
    conv_kernel<<<n / 64, 256, 0, stream>>>(zh, Wm[L], bm[L], pm[L], score);
    topk_kernel<<<BG, 256, 0, stream>>>(score, pn + L, sel, tanhv, newid, cnt, P, K);
    pool_gather_kernel<<<BG * C, 256, 0, stream>>>(zh, sel, tanhv, xout[L], pred, K, lc);
    pool_combine_kernel<<<BG, 64, 0, stream>>>(pred, (float*)d_out, K, C);
    if (L < 2) relabel_count_kernel<<<NEDGE / 256, 256, 0, stream>>>(cur_row, cur_col, newid, cnt);
    xin = xout[L];
  }
}

// Round 5
// 551.758 us; speedup vs baseline: 1.7488x; 1.0628x over previous
//
#include <hip/hip_runtime.h>
#include <math.h>

#define BG   128            // graphs
#define NPER 1024           // nodes per graph, level 0
#define HDIM 128            // hidden
#define NEDGE (BG * NPER * 8)
#define NMAX (BG * NPER)    // 131072
#define CAP  48             // per-node edge bucket capacity (Poisson(8) tail ~1e-15)
#define PRE  16             // LDS-prefetched edges per node (P(deg>16) ~ 0.4%)

// ---------------------------------------------------------------------------
// p-norms for the three pooling vectors
// ---------------------------------------------------------------------------

__global__ __launch_bounds__(128) void pnorm_kernel(
    const float* __restrict__ p1, const float* __restrict__ p2,
    const float* __restrict__ p3, float* __restrict__ pn) {
  const float* p = blockIdx.x == 0 ? p1 : (blockIdx.x == 1 ? p2 : p3);
  __shared__ float red[128];
  int t = threadIdx.x;
  float v = p[t];
  red[t] = v * v;
  __syncthreads();
  for (int off = 64; off; off >>= 1) {
    if (t < off) red[t] += red[t + off];
    __syncthreads();
  }
  if (t == 0) pn[blockIdx.x] = sqrtf(red[0]);
}

// ---------------------------------------------------------------------------
// L0: copy edges into mutable arrays + count in-degree (cnt must be zeroed)
// ---------------------------------------------------------------------------

__global__ __launch_bounds__(256) void copy_count_kernel(
    const int* __restrict__ er, const int* __restrict__ ec,
    int* __restrict__ cr, int* __restrict__ cc, int* __restrict__ cnt) {
  int e = blockIdx.x * 256 + threadIdx.x;
  int r = er[e], c = ec[e];
  cr[e] = r;
  cc[e] = c;
  atomicAdd(&cnt[c], 1);
}

// ---------------------------------------------------------------------------
// prep: dinv from counts; zero fill-cursor; init newid = -1
// ---------------------------------------------------------------------------

__global__ __launch_bounds__(256) void prep_kernel(
    const int* __restrict__ cnt, float* __restrict__ dinv,
    int* __restrict__ cursor, int* __restrict__ newid) {
  int i = blockIdx.x * 256 + threadIdx.x;
  dinv[i] = rsqrtf((float)cnt[i] + 1.0f);
  cursor[i] = 0;
  newid[i] = -1;
}

// ---------------------------------------------------------------------------
// fill: bucket CSR with src row + precomputed coefficient (no indirection left)
// ---------------------------------------------------------------------------

__global__ __launch_bounds__(256) void fill_kernel(
    const int* __restrict__ cr, const int* __restrict__ cc,
    const float* __restrict__ dinv, int* __restrict__ cursor,
    int* __restrict__ src, float* __restrict__ coef) {
  int e = blockIdx.x * 256 + threadIdx.x;
  int c = cc[e];
  if (c >= 0) {
    int r = cr[e];
    int pos = atomicAdd(&cursor[c], 1);
    if (pos < CAP) {
      src[(size_t)c * CAP + pos] = r;
      coef[(size_t)c * CAP + pos] = dinv[r] * dinv[c];
    }
  }
}

// ---------------------------------------------------------------------------
// FUSED agg + conv per 64-node tile:
//  phase 1: z[c] = sum_e x[src_e]*coef_e + x[c]*dinv[c]^2  -> LDS sZ (32 KB)
//           (4-deep unroll: 4 gathers in flight per thread)
//  phase 2: h = relu(sZ @ W + b) -> global; score = h . p
// z never touches global memory. 40 KB LDS -> 4 blocks/CU; co-resident
// blocks overlap gather latency with GEMM VALU work (m114-style).
// ---------------------------------------------------------------------------

__global__ __launch_bounds__(256) void agg_conv_kernel(
    const float* __restrict__ x, float* __restrict__ h,
    const int* __restrict__ src, const float* __restrict__ coef,
    const int* __restrict__ deg, const float* __restrict__ dinv,
    const float* __restrict__ W, const float* __restrict__ bias,
    const float* __restrict__ p, float* __restrict__ score, int n) {
  __shared__ float sZ[64 * HDIM];        // 32 KB
  __shared__ int s_src[64 * PRE];        // 4 KB
  __shared__ float s_cf[64 * PRE];       // 4 KB

  int nt = n >> 6;                       // tiles (2048/1024/512, all %8==0)
  int b = blockIdx.x;
  int tile = (b & 7) * (nt >> 3) + (b >> 3);   // XCD swizzle
  int c0 = tile * 64;
  int t = threadIdx.x;

  // ---- edge metadata for 64 nodes -> LDS (1024 entries) ----
  for (int i = t; i < 64 * PRE; i += 256) {
    int nd = i >> 4;
    int e = i & (PRE - 1);
    s_src[i] = src[(size_t)(c0 + nd) * CAP + e];
    s_cf[i] = coef[(size_t)(c0 + nd) * CAP + e];
  }
  __syncthreads();

  // ---- phase 1: gather-accumulate into sZ ----
  const float4* x4 = (const float4*)x;
  int lane = t & 31, half = t >> 5;      // 8 nodes per pass
  float4* sZ4 = (float4*)sZ;
  for (int pass = 0; pass < 8; ++pass) {
    int node = pass * 8 + half;
    int c = c0 + node;
    int d = deg[c];
    if (d > CAP) d = CAP;
    float dc = dinv[c];
    float s = dc * dc;
    float4 xs = x4[(size_t)c * 32 + lane];
    float4 a0 = make_float4(xs.x * s, xs.y * s, xs.z * s, xs.w * s);
    float4 a1 = make_float4(0.f, 0.f, 0.f, 0.f);
    float4 a2 = make_float4(0.f, 0.f, 0.f, 0.f);
    float4 a3 = make_float4(0.f, 0.f, 0.f, 0.f);
    int dp = d < PRE ? d : PRE;
    const int* ms = &s_src[node * PRE];
    const float* mc = &s_cf[node * PRE];
    int e = 0;
    for (; e + 3 < dp; e += 4) {
      int r0 = ms[e], r1 = ms[e + 1], r2 = ms[e + 2], r3 = ms[e + 3];
      float f0 = mc[e], f1 = mc[e + 1], f2 = mc[e + 2], f3 = mc[e + 3];
      float4 v0 = x4[(size_t)r0 * 32 + lane];
      float4 v1 = x4[(size_t)r1 * 32 + lane];
      float4 v2 = x4[(size_t)r2 * 32 + lane];
      float4 v3 = x4[(size_t)r3 * 32 + lane];
      a0.x = fmaf(v0.x, f0, a0.x); a0.y = fmaf(v0.y, f0, a0.y);
      a0.z = fmaf(v0.z, f0, a0.z); a0.w = fmaf(v0.w, f0, a0.w);
      a1.x = fmaf(v1.x, f1, a1.x); a1.y = fmaf(v1.y, f1, a1.y);
      a1.z = fmaf(v1.z, f1, a1.z); a1.w = fmaf(v1.w, f1, a1.w);
      a2.x = fmaf(v2.x, f2, a2.x); a2.y = fmaf(v2.y, f2, a2.y);
      a2.z = fmaf(v2.z, f2, a2.z); a2.w = fmaf(v2.w, f2, a2.w);
      a3.x = fmaf(v3.x, f3, a3.x); a3.y = fmaf(v3.y, f3, a3.y);
      a3.z = fmaf(v3.z, f3, a3.z); a3.w = fmaf(v3.w, f3, a3.w);
    }
    for (; e < dp; ++e) {
      int r0 = ms[e];
      float f0 = mc[e];
      float4 v0 = x4[(size_t)r0 * 32 + lane];
      a0.x = fmaf(v0.x, f0, a0.x); a0.y = fmaf(v0.y, f0, a0.y);
      a0.z = fmaf(v0.z, f0, a0.z); a0.w = fmaf(v0.w, f0, a0.w);
    }
    for (e = PRE; e < d; ++e) {          // rare tail (deg > 16)
      int r0 = src[(size_t)c * CAP + e];
      float f0 = coef[(size_t)c * CAP + e];
      float4 v0 = x4[(size_t)r0 * 32 + lane];
      a0.x = fmaf(v0.x, f0, a0.x); a0.y = fmaf(v0.y, f0, a0.y);
      a0.z = fmaf(v0.z, f0, a0.z); a0.w = fmaf(v0.w, f0, a0.w);
    }
    float4 o = make_float4(a0.x + a1.x + a2.x + a3.x,
                           a0.y + a1.y + a2.y + a3.y,
                           a0.z + a1.z + a2.z + a3.z,
                           a0.w + a1.w + a2.w + a3.w);
    sZ4[node * 32 + lane] = o;
  }
  __syncthreads();

  // ---- phase 2: GEMM from LDS, fused bias+relu+score ----
  int col_t = t & 31;
  int row_t = t >> 5;
  int r0 = row_t * 8;
  const float4* W4 = (const float4*)W;

  float acc[8][4];
  #pragma unroll
  for (int r = 0; r < 8; ++r)
    #pragma unroll
    for (int c = 0; c < 4; ++c) acc[r][c] = 0.f;

  for (int k4 = 0; k4 < 32; ++k4) {
    float4 w0 = W4[(k4 * 4 + 0) * 32 + col_t];
    float4 w1 = W4[(k4 * 4 + 1) * 32 + col_t];
    float4 w2 = W4[(k4 * 4 + 2) * 32 + col_t];
    float4 w3 = W4[(k4 * 4 + 3) * 32 + col_t];
    #pragma unroll
    for (int r = 0; r < 8; ++r) {
      float4 zr = sZ4[(r0 + r) * 32 + k4];
      acc[r][0] = fmaf(zr.x, w0.x, acc[r][0]);
      acc[r][1] = fmaf(zr.x, w0.y, acc[r][1]);
      acc[r][2] = fmaf(zr.x, w0.z, acc[r][2]);
      acc[r][3] = fmaf(zr.x, w0.w, acc[r][3]);
      acc[r][0] = fmaf(zr.y, w1.x, acc[r][0]);
      acc[r][1] = fmaf(zr.y, w1.y, acc[r][1]);
      acc[r][2] = fmaf(zr.y, w1.z, acc[r][2]);
      acc[r][3] = fmaf(zr.y, w1.w, acc[r][3]);
      acc[r][0] = fmaf(zr.z, w2.x, acc[r][0]);
      acc[r][1] = fmaf(zr.z, w2.y, acc[r][1]);
      acc[r][2] = fmaf(zr.z, w2.z, acc[r][2]);
      acc[r][3] = fmaf(zr.z, w2.w, acc[r][3]);
      acc[r][0] = fmaf(zr.w, w3.x, acc[r][0]);
      acc[r][1] = fmaf(zr.w, w3.y, acc[r][1]);
      acc[r][2] = fmaf(zr.w, w3.z, acc[r][2]);
      acc[r][3] = fmaf(zr.w, w3.w, acc[r][3]);
    }
  }

  float4 bv = ((const float4*)bias)[col_t];
  float4 pv = ((const float4*)p)[col_t];
  float4* out4 = (float4*)(h + (size_t)c0 * HDIM);
  #pragma unroll
  for (int r = 0; r < 8; ++r) {
    float hx = fmaxf(acc[r][0] + bv.x, 0.f);
    float hy = fmaxf(acc[r][1] + bv.y, 0.f);
    float hz = fmaxf(acc[r][2] + bv.z, 0.f);
    float hw = fmaxf(acc[r][3] + bv.w, 0.f);
    float part = hx * pv.x + hy * pv.y + hz * pv.z + hw * pv.w;
    #pragma unroll
    for (int sft = 1; sft < 32; sft <<= 1) part += __shfl_xor(part, sft);
    out4[(r0 + r) * 32 + col_t] = make_float4(hx, hy, hz, hw);
    if (col_t == 0) score[c0 + r0 + r] = part;
  }
}

// ---------------------------------------------------------------------------
// per-graph top-K (K = P/2) by bitonic sort, descending, tie-break lower index
// also zeroes cnt[0 .. BG*K) for the next layer's relabel_count
// ---------------------------------------------------------------------------

__global__ __launch_bounds__(256) void topk_kernel(
    const float* __restrict__ score, const float* __restrict__ pnorm,
    int* __restrict__ sel, float* __restrict__ tanhv, int* __restrict__ newid,
    int* __restrict__ cnt_next, int P, int K) {
  __shared__ float sv[1024];
  __shared__ int si[1024];
  int g = blockIdx.x;
  int t = threadIdx.x;
  for (int j = t; j < K; j += 256) cnt_next[g * K + j] = 0;
  for (int i = t; i < P; i += 256) {
    sv[i] = score[(size_t)g * P + i];
    si[i] = i;
  }
  for (int size = 2; size <= P; size <<= 1) {
    for (int stride = size >> 1; stride; stride >>= 1) {
      __syncthreads();
      for (int i = t; i < P; i += 256) {
        int j = i ^ stride;
        if (j > i) {
          float a = sv[i], b = sv[j];
          int ia = si[i], ib = si[j];
          bool tFirst = (a > b) || (a == b && ia < ib);
          bool up = ((i & size) == 0);
          if (up ? !tFirst : tFirst) {
            sv[i] = b; sv[j] = a;
            si[i] = ib; si[j] = ia;
          }
        }
      }
    }
  }
  __syncthreads();
  float pn = pnorm[0];
  for (int j = t; j < K; j += 256) {
    float v = sv[j];
    int oldg = g * P + si[j];
    int newg = g * K + j;
    sel[newg] = oldg;
    tanhv[newg] = tanhf(v / pn);
    newid[oldg] = newg;
  }
}

// ---------------------------------------------------------------------------
// pool gather: xo[j] = h[sel[j]] * tanhv[j] for a 16-row chunk; float4 lanes.
// grid = BG * (K/16); block 256: lane = t&31 -> channels 4*lane, slot = t>>5
// covers rows {slot, slot+8}; per-chunk partial max/sum to pred
// ---------------------------------------------------------------------------

__global__ __launch_bounds__(256) void pool_gather_kernel(
    const float* __restrict__ h, const int* __restrict__ sel,
    const float* __restrict__ tanhv, float* __restrict__ xo,
    float* __restrict__ pred, int K, int lc) {
  __shared__ int s_sel[16];
  __shared__ float s_th[16];
  __shared__ float4 smx[8][32], ssm[8][32];
  int b = blockIdx.x;
  int g = b >> lc;
  int chunk = b & ((1 << lc) - 1);
  int t = threadIdx.x;
  int j0 = chunk * 16;
  if (t < 16) {
    s_sel[t] = sel[g * K + j0 + t];
    s_th[t] = tanhv[g * K + j0 + t];
  }
  __syncthreads();
  int lane = t & 31, slot = t >> 5;
  const float4* h4 = (const float4*)h;
  float4* xo4 = (float4*)xo;
  float4 mx = make_float4(-INFINITY, -INFINITY, -INFINITY, -INFINITY);
  float4 sm = make_float4(0.f, 0.f, 0.f, 0.f);
  #pragma unroll
  for (int i = 0; i < 2; ++i) {
    int j = slot + i * 8;
    float th = s_th[j];
    float4 v = h4[(size_t)s_sel[j] * 32 + lane];
    v.x *= th; v.y *= th; v.z *= th; v.w *= th;
    xo4[(size_t)(g * K + j0 + j) * 32 + lane] = v;
    mx.x = fmaxf(mx.x, v.x); mx.y = fmaxf(mx.y, v.y);
    mx.z = fmaxf(mx.z, v.z); mx.w = fmaxf(mx.w, v.w);
    sm.x += v.x; sm.y += v.y; sm.z += v.z; sm.w += v.w;
  }
  smx[slot][lane] = mx;
  ssm[slot][lane] = sm;
  __syncthreads();
  if (slot == 0) {
    #pragma unroll
    for (int s2 = 1; s2 < 8; ++s2) {
      float4 m2 = smx[s2][lane], s3 = ssm[s2][lane];
      mx.x = fmaxf(mx.x, m2.x); mx.y = fmaxf(mx.y, m2.y);
      mx.z = fmaxf(mx.z, m2.z); mx.w = fmaxf(mx.w, m2.w);
      sm.x += s3.x; sm.y += s3.y; sm.z += s3.z; sm.w += s3.w;
    }
    float4* pred4 = (float4*)pred;
    pred4[(size_t)(g * 32 + chunk) * 64 + lane] = mx;
    pred4[(size_t)(g * 32 + chunk) * 64 + 32 + lane] = sm;
  }
}

// ---------------------------------------------------------------------------
// pool combine: reduce C chunk-partials per graph, accumulate into out
// block = 64 threads: t<32 -> max channels 4t.., t>=32 -> sum channels
// ---------------------------------------------------------------------------

__global__ __launch_bounds__(64) void pool_combine_kernel(
    const float* __restrict__ pred, float* __restrict__ out, int K, int C) {
  int g = blockIdx.x;
  int t = threadIdx.x;
  const float4* pred4 = (const float4*)pred;
  float4* out4 = (float4*)out;
  if (t < 32) {
    float4 mx = make_float4(-INFINITY, -INFINITY, -INFINITY, -INFINITY);
    for (int c = 0; c < C; ++c) {
      float4 v = pred4[(size_t)(g * 32 + c) * 64 + t];
      mx.x = fmaxf(mx.x, v.x); mx.y = fmaxf(mx.y, v.y);
      mx.z = fmaxf(mx.z, v.z); mx.w = fmaxf(mx.w, v.w);
    }
    float4 o = out4[g * 64 + t];
    o.x += mx.x; o.y += mx.y; o.z += mx.z; o.w += mx.w;
    out4[g * 64 + t] = o;
  } else {
    int l = t - 32;
    float4 sm = make_float4(0.f, 0.f, 0.f, 0.f);
    for (int c = 0; c < C; ++c) {
      float4 v = pred4[(size_t)(g * 32 + c) * 64 + 32 + l];
      sm.x += v.x; sm.y += v.y; sm.z += v.z; sm.w += v.w;
    }
    float inv = 1.0f / (float)K;
    float4 o = out4[g * 64 + 32 + l];
    o.x += sm.x * inv; o.y += sm.y * inv; o.z += sm.z * inv; o.w += sm.w * inv;
    out4[g * 64 + 32 + l] = o;
  }
}

// ---------------------------------------------------------------------------
// fused relabel + count for next layer (cnt_next zeroed by topk)
// ---------------------------------------------------------------------------

__global__ __launch_bounds__(256) void relabel_count_kernel(
    int* __restrict__ cr, int* __restrict__ cc,
    const int* __restrict__ newid, int* __restrict__ cnt) {
  int e = blockIdx.x * 256 + threadIdx.x;
  int r = cr[e];
  if (r < 0) return;
  int nr = newid[r];
  int nc = newid[cc[e]];
  if (nr < 0 || nc < 0) {
    cr[e] = -1;
    cc[e] = -1;
  } else {
    cr[e] = nr;
    cc[e] = nc;
    atomicAdd(&cnt[nc], 1);
  }
}

// ---------------------------------------------------------------------------
// launch
// ---------------------------------------------------------------------------

extern "C" void kernel_launch(void* const* d_in, const int* in_sizes, int n_in,
                              void* d_out, int out_size, void* d_ws, size_t ws_size,
                              hipStream_t stream) {
  const float* x0 = (const float*)d_in[0];
  const int* erow = (const int*)d_in[1];
  const int* ecol = (const int*)d_in[2];
  const float* Wm[3] = {(const float*)d_in[3], (const float*)d_in[6], (const float*)d_in[9]};
  const float* bm[3] = {(const float*)d_in[4], (const float*)d_in[7], (const float*)d_in[10]};
  const float* pm[3] = {(const float*)d_in[5], (const float*)d_in[8], (const float*)d_in[11]};

  char* w = (char*)d_ws;
  size_t off = 0;
  auto alloc = [&](size_t bytes) -> void* {
    void* ptr = w + off;
    off = (off + bytes + 255) & ~(size_t)255;
    return ptr;
  };
  int* cur_row = (int*)alloc((size_t)NEDGE * 4);
  int* cur_col = (int*)alloc((size_t)NEDGE * 4);
  int* src     = (int*)alloc((size_t)NMAX * CAP * 4);
  float* coef  = (float*)alloc((size_t)NMAX * CAP * 4);
  int* cnt     = (int*)alloc((size_t)NMAX * 4);
  int* cursor  = (int*)alloc((size_t)NMAX * 4);
  float* dinv  = (float*)alloc((size_t)NMAX * 4);
  int* newid   = (int*)alloc((size_t)NMAX * 4);
  float* score = (float*)alloc((size_t)NMAX * 4);
  int* sel     = (int*)alloc((size_t)BG * 512 * 4);
  float* tanhv = (float*)alloc((size_t)BG * 512 * 4);
  float* pn    = (float*)alloc(256);
  float* pred  = (float*)alloc((size_t)BG * 32 * 256 * 4);
  float* zh    = (float*)alloc((size_t)NMAX * HDIM * 4);
  float* x1    = (float*)alloc((size_t)BG * 512 * HDIM * 4);
  float* x2    = (float*)alloc((size_t)BG * 256 * HDIM * 4);
  float* x3    = (float*)alloc((size_t)BG * 128 * HDIM * 4);

  hipMemsetAsync(d_out, 0, (size_t)out_size * 4, stream);
  hipMemsetAsync(cnt, 0, (size_t)NMAX * 4, stream);
  pnorm_kernel<<<3, 128, 0, stream>>>(pm[0], pm[1], pm[2], pn);
  copy_count_kernel<<<NEDGE / 256, 256, 0, stream>>>(erow, ecol, cur_row, cur_col, cnt);

  const float* xin = x0;
  float* xout[3] = {x1, x2, x3};
  int Ps[3] = {1024, 512, 256};
  int LCs[3] = {5, 4, 3};     // log2(K/16)

  for (int L = 0; L < 3; ++L) {
    int P = Ps[L];
    int K = P >> 1;
    int n = BG * P;
    int lc = LCs[L];
    int C = 1 << lc;

    prep_kernel<<<n / 256, 256, 0, stream>>>(cnt, dinv, cursor, newid);
    fill_kernel<<<NEDGE / 256, 256, 0, stream>>>(cur_row, cur_col, dinv, cursor, src, coef);
    agg_conv_kernel<<<n / 64, 256, 0, stream>>>(xin, zh, src, coef, cursor, dinv,
                                                Wm[L], bm[L], pm[L], score, n);
    topk_kernel<<<BG, 256, 0, stream>>>(score, pn + L, sel, tanhv, newid, cnt, P, K);
    pool_gather_kernel<<<BG * C, 256, 0, stream>>>(zh, sel, tanhv, xout[L], pred, K, lc);
    pool_combine_kernel<<<BG, 64, 0, stream>>>(pred, (float*)d_out, K, C);
    if (L < 2) relabel_count_kernel<<<NEDGE / 256, 256, 0, stream>>>(cur_row, cur_col, newid, cnt);
    xin = xout[L];
  }
}

// Round 6
// 535.106 us; speedup vs baseline: 1.8032x; 1.0311x over previous
//
#include <hip/hip_runtime.h>
#include <math.h>

#define BG   128            // graphs
#define NPER 1024           // nodes per graph, level 0
#define HDIM 128            // hidden
#define NEDGE (BG * NPER * 8)
#define NMAX (BG * NPER)    // 131072
#define CAP  48             // per-node edge bucket capacity (Poisson(8) tail ~1e-15)
#define PRE  16             // LDS-prefetched edges per node (P(deg>16) ~ 0.4%)
#define TR   32             // agg_conv tile rows (LDS 20.5 KB -> ~7 blocks/CU)

// ---------------------------------------------------------------------------
// p-norms for the three pooling vectors
// ---------------------------------------------------------------------------

__global__ __launch_bounds__(128) void pnorm_kernel(
    const float* __restrict__ p1, const float* __restrict__ p2,
    const float* __restrict__ p3, float* __restrict__ pn) {
  const float* p = blockIdx.x == 0 ? p1 : (blockIdx.x == 1 ? p2 : p3);
  __shared__ float red[128];
  int t = threadIdx.x;
  float v = p[t];
  red[t] = v * v;
  __syncthreads();
  for (int off = 64; off; off >>= 1) {
    if (t < off) red[t] += red[t + off];
    __syncthreads();
  }
  if (t == 0) pn[blockIdx.x] = sqrtf(red[0]);
}

// ---------------------------------------------------------------------------
// L0 in-degree count straight from the input edge list (cnt pre-zeroed)
// ---------------------------------------------------------------------------

__global__ __launch_bounds__(256) void count_kernel(
    const int* __restrict__ ec, int* __restrict__ cnt) {
  int e = blockIdx.x * 256 + threadIdx.x;
  atomicAdd(&cnt[ec[e]], 1);
}

// ---------------------------------------------------------------------------
// prep: dinv from counts; zero fill-cursor; init newid = -1
// ---------------------------------------------------------------------------

__global__ __launch_bounds__(256) void prep_kernel(
    const int* __restrict__ cnt, float* __restrict__ dinv,
    int* __restrict__ cursor, int* __restrict__ newid) {
  int i = blockIdx.x * 256 + threadIdx.x;
  dinv[i] = rsqrtf((float)cnt[i] + 1.0f);
  cursor[i] = 0;
  newid[i] = -1;
}

// ---------------------------------------------------------------------------
// fill: bucket CSR with src row + precomputed coefficient (no indirection left)
// ---------------------------------------------------------------------------

__global__ __launch_bounds__(256) void fill_kernel(
    const int* __restrict__ cr, const int* __restrict__ cc,
    const float* __restrict__ dinv, int* __restrict__ cursor,
    int* __restrict__ src, float* __restrict__ coef) {
  int e = blockIdx.x * 256 + threadIdx.x;
  int c = cc[e];
  if (c >= 0) {
    int r = cr[e];
    int pos = atomicAdd(&cursor[c], 1);
    if (pos < CAP) {
      src[(size_t)c * CAP + pos] = r;
      coef[(size_t)c * CAP + pos] = dinv[r] * dinv[c];
    }
  }
}

// ---------------------------------------------------------------------------
// FUSED agg + conv per 32-node tile:
//  phase 1: z[c] = sum_e x[src_e]*coef_e + x[c]*dinv[c]^2  -> LDS sZ (16 KB)
//  phase 2: h = relu(sZ @ W + b) -> global; score = h . p
// 20.5 KB LDS -> ~7 blocks/CU: enough resident waves for gather-latency
// hiding AND inter-block gather/GEMM overlap (fixes round-5 occupancy loss)
// ---------------------------------------------------------------------------

__global__ __launch_bounds__(256) void agg_conv_kernel(
    const float* __restrict__ x, float* __restrict__ h,
    const int* __restrict__ src, const float* __restrict__ coef,
    const int* __restrict__ deg, const float* __restrict__ dinv,
    const float* __restrict__ W, const float* __restrict__ bias,
    const float* __restrict__ p, float* __restrict__ score, int n) {
  __shared__ float sZ[TR * HDIM];        // 16 KB
  __shared__ int s_src[TR * PRE];        // 2 KB
  __shared__ float s_cf[TR * PRE];       // 2 KB

  int nt = n >> 5;                       // tiles (4096/2048/1024, all %8==0)
  int b = blockIdx.x;
  int tile = (b & 7) * (nt >> 3) + (b >> 3);   // XCD swizzle
  int c0 = tile * TR;
  int t = threadIdx.x;

  // ---- edge metadata for 32 nodes -> LDS (512 entries) ----
  for (int i = t; i < TR * PRE; i += 256) {
    int nd = i >> 4;
    int e = i & (PRE - 1);
    s_src[i] = src[(size_t)(c0 + nd) * CAP + e];
    s_cf[i] = coef[(size_t)(c0 + nd) * CAP + e];
  }
  __syncthreads();

  // ---- phase 1: gather-accumulate into sZ ----
  const float4* x4 = (const float4*)x;
  int lane = t & 31, slot = t >> 5;      // 8 nodes per pass
  float4* sZ4 = (float4*)sZ;
  for (int pass = 0; pass < TR / 8; ++pass) {
    int node = pass * 8 + slot;
    int c = c0 + node;
    int d = deg[c];
    if (d > CAP) d = CAP;
    float dc = dinv[c];
    float s = dc * dc;
    float4 xs = x4[(size_t)c * 32 + lane];
    float4 a0 = make_float4(xs.x * s, xs.y * s, xs.z * s, xs.w * s);
    float4 a1 = make_float4(0.f, 0.f, 0.f, 0.f);
    float4 a2 = make_float4(0.f, 0.f, 0.f, 0.f);
    float4 a3 = make_float4(0.f, 0.f, 0.f, 0.f);
    int dp = d < PRE ? d : PRE;
    const int* ms = &s_src[node * PRE];
    const float* mc = &s_cf[node * PRE];
    int e = 0;
    for (; e + 3 < dp; e += 4) {
      int r0 = ms[e], r1 = ms[e + 1], r2 = ms[e + 2], r3 = ms[e + 3];
      float f0 = mc[e], f1 = mc[e + 1], f2 = mc[e + 2], f3 = mc[e + 3];
      float4 v0 = x4[(size_t)r0 * 32 + lane];
      float4 v1 = x4[(size_t)r1 * 32 + lane];
      float4 v2 = x4[(size_t)r2 * 32 + lane];
      float4 v3 = x4[(size_t)r3 * 32 + lane];
      a0.x = fmaf(v0.x, f0, a0.x); a0.y = fmaf(v0.y, f0, a0.y);
      a0.z = fmaf(v0.z, f0, a0.z); a0.w = fmaf(v0.w, f0, a0.w);
      a1.x = fmaf(v1.x, f1, a1.x); a1.y = fmaf(v1.y, f1, a1.y);
      a1.z = fmaf(v1.z, f1, a1.z); a1.w = fmaf(v1.w, f1, a1.w);
      a2.x = fmaf(v2.x, f2, a2.x); a2.y = fmaf(v2.y, f2, a2.y);
      a2.z = fmaf(v2.z, f2, a2.z); a2.w = fmaf(v2.w, f2, a2.w);
      a3.x = fmaf(v3.x, f3, a3.x); a3.y = fmaf(v3.y, f3, a3.y);
      a3.z = fmaf(v3.z, f3, a3.z); a3.w = fmaf(v3.w, f3, a3.w);
    }
    for (; e < dp; ++e) {
      int r0 = ms[e];
      float f0 = mc[e];
      float4 v0 = x4[(size_t)r0 * 32 + lane];
      a0.x = fmaf(v0.x, f0, a0.x); a0.y = fmaf(v0.y, f0, a0.y);
      a0.z = fmaf(v0.z, f0, a0.z); a0.w = fmaf(v0.w, f0, a0.w);
    }
    for (e = PRE; e < d; ++e) {          // rare tail (deg > 16)
      int r0 = src[(size_t)c * CAP + e];
      float f0 = coef[(size_t)c * CAP + e];
      float4 v0 = x4[(size_t)r0 * 32 + lane];
      a0.x = fmaf(v0.x, f0, a0.x); a0.y = fmaf(v0.y, f0, a0.y);
      a0.z = fmaf(v0.z, f0, a0.z); a0.w = fmaf(v0.w, f0, a0.w);
    }
    float4 o = make_float4(a0.x + a1.x + a2.x + a3.x,
                           a0.y + a1.y + a2.y + a3.y,
                           a0.z + a1.z + a2.z + a3.z,
                           a0.w + a1.w + a2.w + a3.w);
    sZ4[node * 32 + lane] = o;
  }
  __syncthreads();

  // ---- phase 2: GEMM from LDS, fused bias+relu+score ----
  int col_t = t & 31;
  int row_t = t >> 5;
  int r0 = row_t * 4;
  const float4* W4 = (const float4*)W;

  float acc[4][4];
  #pragma unroll
  for (int r = 0; r < 4; ++r)
    #pragma unroll
    for (int c = 0; c < 4; ++c) acc[r][c] = 0.f;

  for (int k4 = 0; k4 < 32; ++k4) {
    float4 w0 = W4[(k4 * 4 + 0) * 32 + col_t];
    float4 w1 = W4[(k4 * 4 + 1) * 32 + col_t];
    float4 w2 = W4[(k4 * 4 + 2) * 32 + col_t];
    float4 w3 = W4[(k4 * 4 + 3) * 32 + col_t];
    #pragma unroll
    for (int r = 0; r < 4; ++r) {
      float4 zr = sZ4[(r0 + r) * 32 + k4];
      acc[r][0] = fmaf(zr.x, w0.x, acc[r][0]);
      acc[r][1] = fmaf(zr.x, w0.y, acc[r][1]);
      acc[r][2] = fmaf(zr.x, w0.z, acc[r][2]);
      acc[r][3] = fmaf(zr.x, w0.w, acc[r][3]);
      acc[r][0] = fmaf(zr.y, w1.x, acc[r][0]);
      acc[r][1] = fmaf(zr.y, w1.y, acc[r][1]);
      acc[r][2] = fmaf(zr.y, w1.z, acc[r][2]);
      acc[r][3] = fmaf(zr.y, w1.w, acc[r][3]);
      acc[r][0] = fmaf(zr.z, w2.x, acc[r][0]);
      acc[r][1] = fmaf(zr.z, w2.y, acc[r][1]);
      acc[r][2] = fmaf(zr.z, w2.z, acc[r][2]);
      acc[r][3] = fmaf(zr.z, w2.w, acc[r][3]);
      acc[r][0] = fmaf(zr.w, w3.x, acc[r][0]);
      acc[r][1] = fmaf(zr.w, w3.y, acc[r][1]);
      acc[r][2] = fmaf(zr.w, w3.z, acc[r][2]);
      acc[r][3] = fmaf(zr.w, w3.w, acc[r][3]);
    }
  }

  float4 bv = ((const float4*)bias)[col_t];
  float4 pv = ((const float4*)p)[col_t];
  float4* out4 = (float4*)(h + (size_t)c0 * HDIM);
  #pragma unroll
  for (int r = 0; r < 4; ++r) {
    float hx = fmaxf(acc[r][0] + bv.x, 0.f);
    float hy = fmaxf(acc[r][1] + bv.y, 0.f);
    float hz = fmaxf(acc[r][2] + bv.z, 0.f);
    float hw = fmaxf(acc[r][3] + bv.w, 0.f);
    float part = hx * pv.x + hy * pv.y + hz * pv.z + hw * pv.w;
    #pragma unroll
    for (int sft = 1; sft < 32; sft <<= 1) part += __shfl_xor(part, sft);
    out4[(r0 + r) * 32 + col_t] = make_float4(hx, hy, hz, hw);
    if (col_t == 0) score[c0 + r0 + r] = part;
  }
}

// ---------------------------------------------------------------------------
// per-graph top-K (K = P/2): P-thread bitonic sort, one element per thread,
// one compare-exchange pass per stage (55 passes at P=1024).
// descending, tie-break lower index. Also zeroes cnt for next layer.
// ---------------------------------------------------------------------------

__global__ __launch_bounds__(1024) void topk_kernel(
    const float* __restrict__ score, const float* __restrict__ pnorm,
    int* __restrict__ sel, float* __restrict__ tanhv, int* __restrict__ newid,
    int* __restrict__ cnt_next, int P, int K) {
  __shared__ float sv[1024];
  __shared__ int si[1024];
  int g = blockIdx.x;
  int t = threadIdx.x;
  if (t < K) cnt_next[g * K + t] = 0;
  sv[t] = score[(size_t)g * P + t];
  si[t] = t;
  for (int size = 2; size <= P; size <<= 1) {
    for (int stride = size >> 1; stride; stride >>= 1) {
      __syncthreads();
      int j = t ^ stride;
      if (j > t) {
        float a = sv[t], b = sv[j];
        int ia = si[t], ib = si[j];
        bool tFirst = (a > b) || (a == b && ia < ib);
        bool up = ((t & size) == 0);
        if (up ? !tFirst : tFirst) {
          sv[t] = b; sv[j] = a;
          si[t] = ib; si[j] = ia;
        }
      }
    }
  }
  __syncthreads();
  if (t < K) {
    float v = sv[t];
    int oldg = g * P + si[t];
    int newg = g * K + t;
    sel[newg] = oldg;
    tanhv[newg] = tanhf(v / pnorm[0]);
    newid[oldg] = newg;
  }
}

// ---------------------------------------------------------------------------
// pool gather: xo[j] = h[sel[j]] * tanhv[j] for a 16-row chunk; float4 lanes.
// grid = BG * (K/16); block 256: lane = t&31 -> channels 4*lane, slot = t>>5
// covers rows {slot, slot+8}; per-chunk partial max/sum to pred
// ---------------------------------------------------------------------------

__global__ __launch_bounds__(256) void pool_gather_kernel(
    const float* __restrict__ h, const int* __restrict__ sel,
    const float* __restrict__ tanhv, float* __restrict__ xo,
    float* __restrict__ pred, int K, int lc) {
  __shared__ int s_sel[16];
  __shared__ float s_th[16];
  __shared__ float4 smx[8][32], ssm[8][32];
  int b = blockIdx.x;
  int g = b >> lc;
  int chunk = b & ((1 << lc) - 1);
  int t = threadIdx.x;
  int j0 = chunk * 16;
  if (t < 16) {
    s_sel[t] = sel[g * K + j0 + t];
    s_th[t] = tanhv[g * K + j0 + t];
  }
  __syncthreads();
  int lane = t & 31, slot = t >> 5;
  const float4* h4 = (const float4*)h;
  float4* xo4 = (float4*)xo;
  float4 mx = make_float4(-INFINITY, -INFINITY, -INFINITY, -INFINITY);
  float4 sm = make_float4(0.f, 0.f, 0.f, 0.f);
  #pragma unroll
  for (int i = 0; i < 2; ++i) {
    int j = slot + i * 8;
    float th = s_th[j];
    float4 v = h4[(size_t)s_sel[j] * 32 + lane];
    v.x *= th; v.y *= th; v.z *= th; v.w *= th;
    xo4[(size_t)(g * K + j0 + j) * 32 + lane] = v;
    mx.x = fmaxf(mx.x, v.x); mx.y = fmaxf(mx.y, v.y);
    mx.z = fmaxf(mx.z, v.z); mx.w = fmaxf(mx.w, v.w);
    sm.x += v.x; sm.y += v.y; sm.z += v.z; sm.w += v.w;
  }
  smx[slot][lane] = mx;
  ssm[slot][lane] = sm;
  __syncthreads();
  if (slot == 0) {
    #pragma unroll
    for (int s2 = 1; s2 < 8; ++s2) {
      float4 m2 = smx[s2][lane], s3 = ssm[s2][lane];
      mx.x = fmaxf(mx.x, m2.x); mx.y = fmaxf(mx.y, m2.y);
      mx.z = fmaxf(mx.z, m2.z); mx.w = fmaxf(mx.w, m2.w);
      sm.x += s3.x; sm.y += s3.y; sm.z += s3.z; sm.w += s3.w;
    }
    float4* pred4 = (float4*)pred;
    pred4[(size_t)(g * 32 + chunk) * 64 + lane] = mx;
    pred4[(size_t)(g * 32 + chunk) * 64 + 32 + lane] = sm;
  }
}

// ---------------------------------------------------------------------------
// pool combine: reduce C chunk-partials per graph, accumulate into out
// block = 64 threads: t<32 -> max channels 4t.., t>=32 -> sum channels
// ---------------------------------------------------------------------------

__global__ __launch_bounds__(64) void pool_combine_kernel(
    const float* __restrict__ pred, float* __restrict__ out, int K, int C) {
  int g = blockIdx.x;
  int t = threadIdx.x;
  const float4* pred4 = (const float4*)pred;
  float4* out4 = (float4*)out;
  if (t < 32) {
    float4 mx = make_float4(-INFINITY, -INFINITY, -INFINITY, -INFINITY);
    for (int c = 0; c < C; ++c) {
      float4 v = pred4[(size_t)(g * 32 + c) * 64 + t];
      mx.x = fmaxf(mx.x, v.x); mx.y = fmaxf(mx.y, v.y);
      mx.z = fmaxf(mx.z, v.z); mx.w = fmaxf(mx.w, v.w);
    }
    float4 o = out4[g * 64 + t];
    o.x += mx.x; o.y += mx.y; o.z += mx.z; o.w += mx.w;
    out4[g * 64 + t] = o;
  } else {
    int l = t - 32;
    float4 sm = make_float4(0.f, 0.f, 0.f, 0.f);
    for (int c = 0; c < C; ++c) {
      float4 v = pred4[(size_t)(g * 32 + c) * 64 + 32 + l];
      sm.x += v.x; sm.y += v.y; sm.z += v.z; sm.w += v.w;
    }
    float inv = 1.0f / (float)K;
    float4 o = out4[g * 64 + 32 + l];
    o.x += sm.x * inv; o.y += sm.y * inv; o.z += sm.z * inv; o.w += sm.w * inv;
    out4[g * 64 + 32 + l] = o;
  }
}

// ---------------------------------------------------------------------------
// fused relabel + count for next layer (cnt zeroed by topk); separate in/out
// so L0 can read the pristine inputs and write the mutable arrays
// ---------------------------------------------------------------------------

__global__ __launch_bounds__(256) void relabel_count_kernel(
    const int* __restrict__ in_r, const int* __restrict__ in_c,
    int* __restrict__ out_r, int* __restrict__ out_c,
    const int* __restrict__ newid, int* __restrict__ cnt) {
  int e = blockIdx.x * 256 + threadIdx.x;
  int r = in_r[e];
  if (r < 0) {
    out_r[e] = -1;
    out_c[e] = -1;
    return;
  }
  int nr = newid[r];
  int nc = newid[in_c[e]];
  if (nr < 0 || nc < 0) {
    out_r[e] = -1;
    out_c[e] = -1;
  } else {
    out_r[e] = nr;
    out_c[e] = nc;
    atomicAdd(&cnt[nc], 1);
  }
}

// ---------------------------------------------------------------------------
// launch
// ---------------------------------------------------------------------------

extern "C" void kernel_launch(void* const* d_in, const int* in_sizes, int n_in,
                              void* d_out, int out_size, void* d_ws, size_t ws_size,
                              hipStream_t stream) {
  const float* x0 = (const float*)d_in[0];
  const int* erow = (const int*)d_in[1];
  const int* ecol = (const int*)d_in[2];
  const float* Wm[3] = {(const float*)d_in[3], (const float*)d_in[6], (const float*)d_in[9]};
  const float* bm[3] = {(const float*)d_in[4], (const float*)d_in[7], (const float*)d_in[10]};
  const float* pm[3] = {(const float*)d_in[5], (const float*)d_in[8], (const float*)d_in[11]};

  char* w = (char*)d_ws;
  size_t off = 0;
  auto alloc = [&](size_t bytes) -> void* {
    void* ptr = w + off;
    off = (off + bytes + 255) & ~(size_t)255;
    return ptr;
  };
  int* cur_row = (int*)alloc((size_t)NEDGE * 4);
  int* cur_col = (int*)alloc((size_t)NEDGE * 4);
  int* src     = (int*)alloc((size_t)NMAX * CAP * 4);
  float* coef  = (float*)alloc((size_t)NMAX * CAP * 4);
  int* cnt     = (int*)alloc((size_t)NMAX * 4);
  int* cursor  = (int*)alloc((size_t)NMAX * 4);
  float* dinv  = (float*)alloc((size_t)NMAX * 4);
  int* newid   = (int*)alloc((size_t)NMAX * 4);
  float* score = (float*)alloc((size_t)NMAX * 4);
  int* sel     = (int*)alloc((size_t)BG * 512 * 4);
  float* tanhv = (float*)alloc((size_t)BG * 512 * 4);
  float* pn    = (float*)alloc(256);
  float* pred  = (float*)alloc((size_t)BG * 32 * 256 * 4);
  float* zh    = (float*)alloc((size_t)NMAX * HDIM * 4);
  float* x1    = (float*)alloc((size_t)BG * 512 * HDIM * 4);
  float* x2    = (float*)alloc((size_t)BG * 256 * HDIM * 4);
  float* x3    = (float*)alloc((size_t)BG * 128 * HDIM * 4);

  hipMemsetAsync(d_out, 0, (size_t)out_size * 4, stream);
  hipMemsetAsync(cnt, 0, (size_t)NMAX * 4, stream);
  pnorm_kernel<<<3, 128, 0, stream>>>(pm[0], pm[1], pm[2], pn);
  count_kernel<<<NEDGE / 256, 256, 0, stream>>>(ecol, cnt);

  const float* xin = x0;
  float* xout[3] = {x1, x2, x3};
  int Ps[3] = {1024, 512, 256};
  int LCs[3] = {5, 4, 3};     // log2(K/16)

  for (int L = 0; L < 3; ++L) {
    int P = Ps[L];
    int K = P >> 1;
    int n = BG * P;
    int lc = LCs[L];
    int C = 1 << lc;
    const int* in_r = (L == 0) ? erow : cur_row;
    const int* in_c = (L == 0) ? ecol : cur_col;

    prep_kernel<<<n / 256, 256, 0, stream>>>(cnt, dinv, cursor, newid);
    fill_kernel<<<NEDGE / 256, 256, 0, stream>>>(in_r, in_c, dinv, cursor, src, coef);
    agg_conv_kernel<<<n / TR, 256, 0, stream>>>(xin, zh, src, coef, cursor, dinv,
                                                Wm[L], bm[L], pm[L], score, n);
    topk_kernel<<<BG, P, 0, stream>>>(score, pn + L, sel, tanhv, newid, cnt, P, K);
    pool_gather_kernel<<<BG * C, 256, 0, stream>>>(zh, sel, tanhv, xout[L], pred, K, lc);
    pool_combine_kernel<<<BG, 64, 0, stream>>>(pred, (float*)d_out, K, C);
    if (L < 2) relabel_count_kernel<<<NEDGE / 256, 256, 0, stream>>>(
        in_r, in_c, cur_row, cur_col, newid, cnt);
    xin = xout[L];
  }
}